// Round 11
// baseline (274.501 us; speedup 1.0000x reference)
//
#include <hip/hip_runtime.h>
#include <math.h>

// ---------------------------------------------------------------------------
// Net_1503238553644: 2-layer ChebConv(K=2) GNN + linear skips + edge recon loss
// N=13627, E=504378, F=64, H1=300, H2=100, LIN=100
// R11: CSR-build atomics de-hotspotted: 8-replica deg, 4-group x2-replica cnt,
//      group-partitioned fill cursors (g=(e>>8)&3, per-node-contiguous CSR),
//      int4 edge loads/pair stores. MFMA GEMM + fp8 loss unchanged.
// ---------------------------------------------------------------------------

typedef unsigned short ushort_t;
typedef float v2f __attribute__((ext_vector_type(2)));
typedef short bf16x8 __attribute__((ext_vector_type(8)));
typedef float f32x4 __attribute__((ext_vector_type(4)));

#define GBM 64
#define GBN 64
#define GBK 32
#define LDK 72   // bf16 per LDS row: 144B, 16B-aligned, 2-way bank alias (free)

__device__ inline short f2bf(float f) {              // RNE float->bf16
    unsigned u = __float_as_uint(f);
    u += 0x7fff + ((u >> 16) & 1);
    return (short)(u >> 16);
}
__device__ inline float bflo(unsigned w) { return __uint_as_float(w << 16); }
__device__ inline float bfhi(unsigned w) { return __uint_as_float(w & 0xffff0000u); }

// 8-replica deg hist (by src); 4-group x 2-replica cnt hist (by dst, group
// g=(e>>8)&3 at layout [v*4+g]); packs pp/pn edge pairs. int4 edge loads.
__global__ void deg_hist_pairs_kernel(const int* __restrict__ ei, const int* __restrict__ nei,
                                      int* __restrict__ hist, int* __restrict__ cnt2, int Nal,
                                      int2* __restrict__ pp, int2* __restrict__ pn, int E) {
    int* hd = hist + (size_t)(blockIdx.x & 7) * Nal;
    int* hc = cnt2 + (size_t)(blockIdx.x & 1) * 4 * Nal;
    int stride = gridDim.x * blockDim.x;
    int nq = E >> 2;
    for (int q = blockIdx.x * blockDim.x + threadIdx.x; q < nq; q += stride) {
        int e = q * 4;
        int g = (e >> 8) & 3;                 // same group for e..e+3
        int4 a  = *(const int4*)&ei[e];
        int2 b01 = *(const int2*)&ei[E + e];      // E even -> 8B aligned
        int2 b23 = *(const int2*)&ei[E + e + 2];
        int4 na = *(const int4*)&nei[e];
        int2 nb01 = *(const int2*)&nei[E + e];
        int2 nb23 = *(const int2*)&nei[E + e + 2];
        atomicAdd(&hd[a.x], 1); atomicAdd(&hd[a.y], 1);
        atomicAdd(&hd[a.z], 1); atomicAdd(&hd[a.w], 1);
        atomicAdd(&hc[b01.x * 4 + g], 1); atomicAdd(&hc[b01.y * 4 + g], 1);
        atomicAdd(&hc[b23.x * 4 + g], 1); atomicAdd(&hc[b23.y * 4 + g], 1);
        int4 p1 = {a.x, b01.x, a.y, b01.y};
        int4 p2 = {a.z, b23.x, a.w, b23.y};
        *(int4*)&pp[e] = p1; *(int4*)&pp[e + 2] = p2;
        int4 q1 = {na.x, nb01.x, na.y, nb01.y};
        int4 q2 = {na.z, nb23.x, na.w, nb23.y};
        *(int4*)&pn[e] = q1; *(int4*)&pn[e + 2] = q2;
    }
    int tail = E & 3;
    if (blockIdx.x == 0 && threadIdx.x < tail) {
        int e = (E & ~3) + threadIdx.x;
        int a = ei[e], b = ei[E + e];
        int g = (e >> 8) & 3;
        atomicAdd(&hd[a], 1);
        atomicAdd(&hc[b * 4 + g], 1);
        pp[e] = make_int2(a, b);
        pn[e] = make_int2(nei[e], nei[E + e]);
    }
}

// merge replicas -> dinv, per-node count (rowptr[v+1]) + per-node group prefix pg
__global__ void merge_hist_kernel(const int* __restrict__ hist, const int* __restrict__ cnt2,
                                  int Nal, float* __restrict__ dinv, int* __restrict__ rowptr,
                                  int* __restrict__ pg, int n) {
    int i = blockIdx.x * blockDim.x + threadIdx.x;
    if (i < n) {
        int d = 0;
#pragma unroll
        for (int r = 0; r < 8; ++r) d += hist[(size_t)r * Nal + i];
        dinv[i] = (d > 0) ? (1.0f / sqrtf((float)d)) : 0.0f;
        int4 ca = *(const int4*)&cnt2[(size_t)i * 4];
        int4 cb = *(const int4*)&cnt2[4 * (size_t)Nal + (size_t)i * 4];
        int c0 = ca.x + cb.x, c1 = ca.y + cb.y, c2 = ca.z + cb.z, c3 = ca.w + cb.w;
        int4 p = {0, c0, c0 + c1, c0 + c1 + c2};
        *(int4*)&pg[(size_t)i * 4] = p;
        rowptr[i + 1] = c0 + c1 + c2 + c3;
    }
    if (i == 0) rowptr[0] = 0;
}

// single-block inclusive scan of rowptr[1..n]
__global__ void scan_kernel(int* __restrict__ rowptr, int n) {
    __shared__ int wsum[16];
    __shared__ int carry_s;
    if (threadIdx.x == 0) carry_s = 0;
    __syncthreads();
    int nchunk = (n + 1023) / 1024;
    int wid = threadIdx.x >> 6, lane = threadIdx.x & 63;
    for (int c = 0; c < nchunk; ++c) {
        int i = c * 1024 + threadIdx.x;
        int v = (i < n) ? rowptr[i + 1] : 0;
        int s = v;
        for (int off = 1; off < 64; off <<= 1) {
            int t = __shfl_up(s, off, 64);
            if (lane >= off) s += t;
        }
        if (lane == 63) wsum[wid] = s;
        __syncthreads();
        if (wid == 0 && lane < 16) {
            int wsv = wsum[lane];
            for (int off = 1; off < 16; off <<= 1) {
                int t = __shfl_up(wsv, off, 64);
                if (lane >= off) wsv += t;
            }
            wsum[lane] = wsv;
        }
        __syncthreads();
        int base = carry_s + (wid > 0 ? wsum[wid - 1] : 0);
        int inc = base + s;
        if (i < n) rowptr[i + 1] = inc;
        __syncthreads();
        if (threadIdx.x == 1023) carry_s = inc;
        __syncthreads();
    }
}

// cursor[v*4+g] = rowptr[v] + pg[v*4+g]
__global__ void cursor_init_kernel(const int* __restrict__ rowptr, const int* __restrict__ pg,
                                   int* __restrict__ cursor, int n4) {
    int i = blockIdx.x * blockDim.x + threadIdx.x;
    if (i < n4) cursor[i] = rowptr[i >> 2] + pg[i];
}

// scatter edges into group-partitioned CSR slots (per-node contiguous)
__global__ void fill_kernel(const int* __restrict__ ei, const float* __restrict__ dinv,
                            int* __restrict__ cursor, int* __restrict__ colidx,
                            float* __restrict__ wnorm, int E) {
    int stride = gridDim.x * blockDim.x;
    int nq = E >> 2;
    for (int q = blockIdx.x * blockDim.x + threadIdx.x; q < nq; q += stride) {
        int e = q * 4;
        int g = (e >> 8) & 3;
        int4 s4 = *(const int4*)&ei[e];
        int2 d01 = *(const int2*)&ei[E + e];
        int2 d23 = *(const int2*)&ei[E + e + 2];
        int slot0 = atomicAdd(&cursor[d01.x * 4 + g], 1);
        int slot1 = atomicAdd(&cursor[d01.y * 4 + g], 1);
        int slot2 = atomicAdd(&cursor[d23.x * 4 + g], 1);
        int slot3 = atomicAdd(&cursor[d23.y * 4 + g], 1);
        colidx[slot0] = s4.x; wnorm[slot0] = -dinv[s4.x] * dinv[d01.x];
        colidx[slot1] = s4.y; wnorm[slot1] = -dinv[s4.y] * dinv[d01.y];
        colidx[slot2] = s4.z; wnorm[slot2] = -dinv[s4.z] * dinv[d23.x];
        colidx[slot3] = s4.w; wnorm[slot3] = -dinv[s4.w] * dinv[d23.y];
    }
    int tail = E & 3;
    if (blockIdx.x == 0 && threadIdx.x < tail) {
        int e = (E & ~3) + threadIdx.x;
        int s = ei[e];
        int d = ei[E + e];
        int g = (e >> 8) & 3;
        int slot = atomicAdd(&cursor[d * 4 + g], 1);
        colidx[slot] = s;
        wnorm[slot] = -dinv[s] * dinv[d];
    }
}

// XT[node] = [ x[node] (64) | segsum64(x)[node] (64) ] — one wave per node,
// 4 edges in flight (16-lane groups, float4/lane = full 64-f32 row).
__global__ void xt_kernel(const float* __restrict__ x, const int* __restrict__ rowptr,
                          const int* __restrict__ colidx, const float* __restrict__ wnorm,
                          float* __restrict__ XT, int n) {
    int node = (blockIdx.x * blockDim.x + threadIdx.x) >> 6;
    if (node >= n) return;
    int lane = threadIdx.x & 63;
    int grp = lane >> 4;
    int l = lane & 15;
    int j0 = rowptr[node], j1 = rowptr[node + 1];
    float4 a = {0, 0, 0, 0};
    for (int j = j0 + grp; j < j1; j += 4) {
        int c = colidx[j];
        float w = wnorm[j];
        float4 v = ((const float4*)(x + (size_t)c * 64))[l];
        a.x += w * v.x; a.y += w * v.y; a.z += w * v.z; a.w += w * v.w;
    }
#pragma unroll
    for (int off = 16; off <= 32; off <<= 1) {
        a.x += __shfl_xor(a.x, off, 64);
        a.y += __shfl_xor(a.y, off, 64);
        a.z += __shfl_xor(a.z, off, 64);
        a.w += __shfl_xor(a.w, off, 64);
    }
    if (grp == 0) {
        float4 xv = ((const float4*)(x + (size_t)node * 64))[l];
        *(float4*)&XT[(size_t)node * 128 + l * 4] = xv;
        *(float4*)&XT[(size_t)node * 128 + 64 + l * 4] = a;
    }
}

// C[Nrows x Ncols] = relu?( A @ Bcat + biascat ), bf16 MFMA 64x64x32.
__global__ __launch_bounds__(256) void gemm_mfma(
    const float* __restrict__ A, int lda,
    const float* __restrict__ B0, const float* __restrict__ B1,
    const float* __restrict__ bias0, const float* __restrict__ bias1,
    float* __restrict__ C, int Nrows, int K, int Ncols, int split, int relu) {
    __shared__ short As[GBM * LDK];   // [m][k] bf16
    __shared__ short Bs[GBN * LDK];   // [n][k] bf16 (B transposed)
    const int bm = blockIdx.y * GBM, bn = blockIdx.x * GBN;
    const int tid = threadIdx.x;
    const int w = tid >> 6, l = tid & 63;
    const int wm = (w >> 1) * 32, wn = (w & 1) * 32;
    const int lr = l & 15;
    const int kg = l >> 4;
    const int arow = tid >> 2, aseg = tid & 3;
    const int bcol = tid & 63, bk2 = (tid >> 6) * 2;
    const int ldb0 = split, ldb1 = Ncols - split;

    const int arowg = bm + arow;
    const int bcolg = bn + bcol;
    const float* Bsrc = (bcolg < split) ? (B0 + bcolg)
                       : ((bcolg < Ncols) ? (B1 + (bcolg - split)) : nullptr);
    const int ldb = (bcolg < split) ? ldb0 : ldb1;

    f32x4 acc00 = {0,0,0,0}, acc01 = {0,0,0,0}, acc10 = {0,0,0,0}, acc11 = {0,0,0,0};

    for (int k0 = 0; k0 < K; k0 += GBK) {
        {
            int kk = k0 + aseg * 8;
            bf16x8 v;
            if (arowg < Nrows && kk + 7 < K) {
                float4 f0 = *(const float4*)&A[(size_t)arowg * lda + kk];
                float4 f1 = *(const float4*)&A[(size_t)arowg * lda + kk + 4];
                v[0] = f2bf(f0.x); v[1] = f2bf(f0.y); v[2] = f2bf(f0.z); v[3] = f2bf(f0.w);
                v[4] = f2bf(f1.x); v[5] = f2bf(f1.y); v[6] = f2bf(f1.z); v[7] = f2bf(f1.w);
            } else {
#pragma unroll
                for (int i = 0; i < 8; ++i)
                    v[i] = (arowg < Nrows && kk + i < K)
                         ? f2bf(A[(size_t)arowg * lda + kk + i]) : (short)0;
            }
            *(bf16x8*)&As[arow * LDK + aseg * 8] = v;
        }
#pragma unroll
        for (int q = 0; q < 4; ++q) {
            int k = q * 8 + bk2;
            unsigned pw = 0u;
            if (Bsrc) {
                float f0 = (k0 + k < K) ? Bsrc[(size_t)(k0 + k) * ldb] : 0.0f;
                float f1 = (k0 + k + 1 < K) ? Bsrc[(size_t)(k0 + k + 1) * ldb] : 0.0f;
                pw = (unsigned)(unsigned short)f2bf(f0)
                   | ((unsigned)(unsigned short)f2bf(f1) << 16);
            }
            *(unsigned*)&Bs[bcol * LDK + k] = pw;
        }
        __syncthreads();
        bf16x8 a0 = *(const bf16x8*)&As[(wm + lr) * LDK + kg * 8];
        bf16x8 a1 = *(const bf16x8*)&As[(wm + 16 + lr) * LDK + kg * 8];
        bf16x8 b0 = *(const bf16x8*)&Bs[(wn + lr) * LDK + kg * 8];
        bf16x8 b1 = *(const bf16x8*)&Bs[(wn + 16 + lr) * LDK + kg * 8];
        acc00 = __builtin_amdgcn_mfma_f32_16x16x32_bf16(a0, b0, acc00, 0, 0, 0);
        acc01 = __builtin_amdgcn_mfma_f32_16x16x32_bf16(a0, b1, acc01, 0, 0, 0);
        acc10 = __builtin_amdgcn_mfma_f32_16x16x32_bf16(a1, b0, acc10, 0, 0, 0);
        acc11 = __builtin_amdgcn_mfma_f32_16x16x32_bf16(a1, b1, acc11, 0, 0, 0);
        __syncthreads();
    }
#pragma unroll
    for (int i = 0; i < 2; ++i) {
        int rbase = bm + wm + i * 16 + kg * 4;
#pragma unroll
        for (int j = 0; j < 2; ++j) {
            int col = bn + wn + j * 16 + lr;
            if (col >= Ncols) continue;
            float bv = (col < split) ? (bias0 ? bias0[col] : 0.0f)
                                     : (bias1 ? bias1[col - split] : 0.0f);
            f32x4 a = (i == 0) ? (j == 0 ? acc00 : acc01) : (j == 0 ? acc10 : acc11);
#pragma unroll
            for (int r = 0; r < 4; ++r) {
                int row = rbase + r;
                if (row < Nrows) {
                    float o = a[r] + bv;
                    if (relu) o = fmaxf(o, 0.0f);
                    C[(size_t)row * Ncols + col] = o;
                }
            }
        }
    }
}

// pack src[:, off:off+w] (f32, stride ld) -> dst bf16 rows padded to 128 (zeros)
__global__ void pack_bf16_kernel(const float* __restrict__ src, int ld, int off, int w,
                                 ushort_t* __restrict__ dst, int n) {
    int idx = blockIdx.x * blockDim.x + threadIdx.x;
    if (idx >= n * 32) return;
    int i = idx >> 5, q = idx & 31;
    uint2 p = {0u, 0u};
    if (q * 4 < w) {
        float4 v = *(const float4*)&src[(size_t)i * ld + off + q * 4];
        p.x = (unsigned)(unsigned short)f2bf(v.x) | ((unsigned)(unsigned short)f2bf(v.y) << 16);
        p.y = (unsigned)(unsigned short)f2bf(v.z) | ((unsigned)(unsigned short)f2bf(v.w) << 16);
    }
    *(uint2*)&dst[(size_t)i * 128 + q * 4] = p;
}

// t = segsum(hWb); x1 = relu(G2[:,0:100] + t + b2) — fused epilogue.
__global__ void segsum_combine1_kernel(const ushort_t* __restrict__ hb,
                                       const int* __restrict__ rowptr, const int* __restrict__ colidx,
                                       const float* __restrict__ wnorm,
                                       const float* __restrict__ G2, const float* __restrict__ b2,
                                       float* __restrict__ x1, int n) {
    int node = (blockIdx.x * blockDim.x + threadIdx.x) >> 6;
    if (node >= n) return;
    int lane = threadIdx.x & 63;
    int grp = lane >> 4;
    int l = lane & 15;
    int j0 = rowptr[node], j1 = rowptr[node + 1];
    float acc[8] = {};
    for (int j = j0 + grp; j < j1; j += 4) {
        int c = colidx[j];
        float w = wnorm[j];
        uint4 v = ((const uint4*)(hb + (size_t)c * 128))[l];
        acc[0] += w * bflo(v.x); acc[1] += w * bfhi(v.x);
        acc[2] += w * bflo(v.y); acc[3] += w * bfhi(v.y);
        acc[4] += w * bflo(v.z); acc[5] += w * bfhi(v.z);
        acc[6] += w * bflo(v.w); acc[7] += w * bfhi(v.w);
    }
#pragma unroll
    for (int k = 0; k < 8; ++k) {
        acc[k] += __shfl_xor(acc[k], 16, 64);
        acc[k] += __shfl_xor(acc[k], 32, 64);
    }
    if (grp == 0) {
        int f = l * 8;
        if (f < 100) {
            float4 g0 = *(const float4*)&G2[(size_t)node * 200 + f];
            float4 bv0 = *(const float4*)&b2[f];
            float4 o0;
            o0.x = fmaxf(g0.x + acc[0] + bv0.x, 0.0f);
            o0.y = fmaxf(g0.y + acc[1] + bv0.y, 0.0f);
            o0.z = fmaxf(g0.z + acc[2] + bv0.z, 0.0f);
            o0.w = fmaxf(g0.w + acc[3] + bv0.w, 0.0f);
            *(float4*)&x1[(size_t)node * 100 + f] = o0;
            if (f + 8 <= 100) {
                float4 g1 = *(const float4*)&G2[(size_t)node * 200 + f + 4];
                float4 bv1 = *(const float4*)&b2[f + 4];
                float4 o1;
                o1.x = fmaxf(g1.x + acc[4] + bv1.x, 0.0f);
                o1.y = fmaxf(g1.y + acc[5] + bv1.y, 0.0f);
                o1.z = fmaxf(g1.z + acc[6] + bv1.z, 0.0f);
                o1.w = fmaxf(g1.w + acc[7] + bv1.w, 0.0f);
                *(float4*)&x1[(size_t)node * 100 + f + 4] = o1;
            }
        }
    }
}

// xo = x1 + relu(S[:,0:100]) (f32); zf = fp8(x1 + relu(S[:,100:200]))
__global__ void combine2_kernel(const float* __restrict__ S, const float* __restrict__ x1,
                                float* __restrict__ xo, unsigned* __restrict__ zf, int n) {
    int idx = blockIdx.x * blockDim.x + threadIdx.x;
    if (idx >= n * 32) return;
    int i = idx >> 5, q = idx & 31;
    unsigned w = 0u;
    if (q < 25) {
        float4 s1 = *(const float4*)&S[(size_t)i * 200 + q * 4];
        float4 s2 = *(const float4*)&S[(size_t)i * 200 + 100 + q * 4];
        float4 xv = *(const float4*)&x1[(size_t)i * 100 + q * 4];
        float4 a, b;
        a.x = xv.x + fmaxf(s1.x, 0.0f); a.y = xv.y + fmaxf(s1.y, 0.0f);
        a.z = xv.z + fmaxf(s1.z, 0.0f); a.w = xv.w + fmaxf(s1.w, 0.0f);
        b.x = xv.x + fmaxf(s2.x, 0.0f); b.y = xv.y + fmaxf(s2.y, 0.0f);
        b.z = xv.z + fmaxf(s2.z, 0.0f); b.w = xv.w + fmaxf(s2.w, 0.0f);
        *(float4*)&xo[(size_t)i * 100 + q * 4] = a;
        w = (unsigned)__builtin_amdgcn_cvt_pk_fp8_f32(b.x, b.y, 0, false);
        w = (unsigned)__builtin_amdgcn_cvt_pk_fp8_f32(b.z, b.w, (int)w, true);
    }
    zf[(size_t)i * 32 + q] = w;
}

// fused pos/neg loss on fp8 z rows: 8 lanes/edge, uint4/lane = full 128B row.
__global__ __launch_bounds__(256) void edge_loss_fp8_kernel(
    const unsigned* __restrict__ zf, const int2* __restrict__ pp,
    const int2* __restrict__ pn, int E, float* __restrict__ accv) {
    const int y = blockIdx.y;
    const int2* __restrict__ pairs = y ? pn : pp;
    const int l = threadIdx.x & 7;
    const int g = (blockIdx.x * blockDim.x + threadIdx.x) >> 3;
    const int ng = (gridDim.x * blockDim.x) >> 3;
    float s = 0.0f;
    int niter = (g < E) ? ((E - 1 - g) / ng + 1) : 0;
    if (niter > 0) {
        int eclamp1 = (g + ng < E) ? (g + ng) : (E - 1);
        int2 p0 = pairs[g];
        int2 p1 = pairs[eclamp1];
        uint4 ra0 = *(const uint4*)&zf[(size_t)p0.x * 32 + l * 4];
        uint4 rb0 = *(const uint4*)&zf[(size_t)p0.y * 32 + l * 4];
        for (int t = 0; t < niter; ++t) {
            int e2 = g + (t + 2) * ng;
            e2 = (e2 < E) ? e2 : (E - 1);
            int2 p2 = pairs[e2];
            uint4 ra1 = *(const uint4*)&zf[(size_t)p1.x * 32 + l * 4];
            uint4 rb1 = *(const uint4*)&zf[(size_t)p1.y * 32 + l * 4];
            float dot = 0.0f;
            v2f fa, fb;
            fa = __builtin_amdgcn_cvt_pk_f32_fp8(ra0.x, false);
            fb = __builtin_amdgcn_cvt_pk_f32_fp8(rb0.x, false);
            dot += fa.x * fb.x + fa.y * fb.y;
            fa = __builtin_amdgcn_cvt_pk_f32_fp8(ra0.x, true);
            fb = __builtin_amdgcn_cvt_pk_f32_fp8(rb0.x, true);
            dot += fa.x * fb.x + fa.y * fb.y;
            fa = __builtin_amdgcn_cvt_pk_f32_fp8(ra0.y, false);
            fb = __builtin_amdgcn_cvt_pk_f32_fp8(rb0.y, false);
            dot += fa.x * fb.x + fa.y * fb.y;
            fa = __builtin_amdgcn_cvt_pk_f32_fp8(ra0.y, true);
            fb = __builtin_amdgcn_cvt_pk_f32_fp8(rb0.y, true);
            dot += fa.x * fb.x + fa.y * fb.y;
            fa = __builtin_amdgcn_cvt_pk_f32_fp8(ra0.z, false);
            fb = __builtin_amdgcn_cvt_pk_f32_fp8(rb0.z, false);
            dot += fa.x * fb.x + fa.y * fb.y;
            fa = __builtin_amdgcn_cvt_pk_f32_fp8(ra0.z, true);
            fb = __builtin_amdgcn_cvt_pk_f32_fp8(rb0.z, true);
            dot += fa.x * fb.x + fa.y * fb.y;
            fa = __builtin_amdgcn_cvt_pk_f32_fp8(ra0.w, false);
            fb = __builtin_amdgcn_cvt_pk_f32_fp8(rb0.w, false);
            dot += fa.x * fb.x + fa.y * fb.y;
            fa = __builtin_amdgcn_cvt_pk_f32_fp8(ra0.w, true);
            fb = __builtin_amdgcn_cvt_pk_f32_fp8(rb0.w, true);
            dot += fa.x * fb.x + fa.y * fb.y;
            dot += __shfl_xor(dot, 1, 8);
            dot += __shfl_xor(dot, 2, 8);
            dot += __shfl_xor(dot, 4, 8);
            if (l == 0) {
                float sg = 1.0f / (1.0f + expf(-dot));
                s += y ? logf(1.0f - sg + 1e-15f) : logf(sg + 1e-15f);
            }
            p1 = p2; ra0 = ra1; rb0 = rb1;
        }
    }
    __shared__ float red[256];
    red[threadIdx.x] = s;
    __syncthreads();
    for (int st = 128; st > 0; st >>= 1) {
        if (threadIdx.x < st) red[threadIdx.x] += red[threadIdx.x + st];
        __syncthreads();
    }
    if (threadIdx.x == 0) atomicAdd(&accv[y], red[0]);
}

// sv[i] = xo[i,:] @ w (100-dim)
__global__ void rowdot_kernel(const float* __restrict__ xo, const float* __restrict__ w,
                              float* __restrict__ s, int n) {
    int i = blockIdx.x * blockDim.x + threadIdx.x;
    if (i >= n) return;
    const float4* a = (const float4*)(xo + (size_t)i * 100);
    const float4* wv = (const float4*)w;
    float acc = 0.0f;
#pragma unroll
    for (int q = 0; q < 25; ++q) {
        float4 va = a[q], vw = wv[q];
        acc += va.x * vw.x + va.y * vw.y + va.z * vw.z + va.w * vw.w;
    }
    s[i] = acc;
}

// out[i] = xo[i,:]@W3[0] + b3 + sum_j wnorm[j]*sv[colidx[j]]
__global__ void out_kernel(const float* __restrict__ xo, const float* __restrict__ W3,
                           const float* __restrict__ b3, const int* __restrict__ rowptr,
                           const int* __restrict__ colidx, const float* __restrict__ wnorm,
                           const float* __restrict__ sv, float* __restrict__ out, int n) {
    int i = blockIdx.x * blockDim.x + threadIdx.x;
    if (i >= n) return;
    const float4* a = (const float4*)(xo + (size_t)i * 100);
    const float4* wv = (const float4*)W3;
    float acc = b3[0];
#pragma unroll
    for (int q = 0; q < 25; ++q) {
        float4 va = a[q], vw = wv[q];
        acc += va.x * vw.x + va.y * vw.y + va.z * vw.z + va.w * vw.w;
    }
    int j1 = rowptr[i + 1];
    for (int j = rowptr[i]; j < j1; ++j)
        acc += wnorm[j] * sv[colidx[j]];
    out[i] = acc;
}

__global__ void finalize_kernel(float* __restrict__ out, const float* __restrict__ acc,
                                const float* __restrict__ c1, const float* __restrict__ c2,
                                int Nn, int E) {
    out[Nn]     = -(acc[0] + acc[1]) / (float)E;
    out[Nn + 1] = c1[0];
    out[Nn + 2] = c2[0];
}

extern "C" void kernel_launch(void* const* d_in, const int* in_sizes, int n_in,
                              void* d_out, int out_size, void* d_ws, size_t ws_size,
                              hipStream_t stream) {
    (void)n_in; (void)out_size; (void)ws_size;
    const float* x   = (const float*)d_in[0];
    const int*   ei  = (const int*)d_in[1];
    const int*   nei = (const int*)d_in[2];
    const float* W1  = (const float*)d_in[3];
    const float* b1  = (const float*)d_in[4];
    const float* W2  = (const float*)d_in[5];
    const float* b2  = (const float*)d_in[6];
    const float* W3  = (const float*)d_in[7];
    const float* b3  = (const float*)d_in[8];
    const float* lw1 = (const float*)d_in[9];
    const float* lb1 = (const float*)d_in[10];
    const float* lw2 = (const float*)d_in[11];
    const float* lb2 = (const float*)d_in[12];
    const float* c1  = (const float*)d_in[13];
    const float* c2  = (const float*)d_in[14];

    const int Nn = in_sizes[0] / 64;   // 13627
    const int E  = in_sizes[1] / 2;    // 504378

    const size_t Nal = ((size_t)Nn + 5) & ~(size_t)3;   // >= N+1, mult of 4
    const size_t Eal = ((size_t)E + 3) & ~(size_t)3;

    float* ws     = (float*)d_ws;
    int*   hist   = (int*)ws;                     // 8*Nal ints (deg replicas)
    int*   cnt2   = hist + 8 * Nal;               // 8*Nal ints (4-group x2 rep)
    float* acc    = (float*)(cnt2 + 8 * Nal);     // 4 floats
    float* dinv   = acc + 4;                      // Nal floats
    int*   rowptr = (int*)(dinv + Nal);           // Nal ints (N+1 used)
    int*   pg     = rowptr + Nal;                 // 4*Nal ints
    int*   cursor = pg + 4 * Nal;                 // 4*Nal ints
    int*   colidx = cursor + 4 * Nal;             // Eal ints
    float* wnorm  = (float*)(colidx + Eal);       // Eal floats
    int2*  pp     = (int2*)(wnorm + Eal);         // Eal int2
    int2*  pn     = pp + Eal;                     // Eal int2
    float* XT     = (float*)(pn + Eal);           // N*128
    float* h      = XT + (size_t)Nn * 128;        // N*300 (alias S: N*200)
    float* G2     = h  + (size_t)Nn * 300;        // N*200
    float* x1     = G2 + (size_t)Nn * 200;        // N*100
    float* xo     = x1 + (size_t)Nn * 100;        // N*100
    size_t zoff   = (size_t)(xo + (size_t)Nn * 100 - ws);
    zoff = (zoff + 31) & ~(size_t)31;             // 128B align
    unsigned* zf  = (unsigned*)(ws + zoff);       // N*32 words (fp8 rows, 128B)
    size_t hoff   = zoff + (size_t)Nn * 32 + 63;
    hoff &= ~(size_t)63;                          // 256B align
    ushort_t* hWb = (ushort_t*)(ws + hoff);       // N*128 bf16 (256B rows)
    float* sv     = ws + hoff + (size_t)Nn * 64;  // Nal
    float* S      = h;                            // alias (h dead after conv2 gemm)

    const int MB = (Nn + GBM - 1) / GBM;

    // --- zero hist + cnt2 + acc in one memset ---
    hipMemsetAsync(hist, 0, (16 * Nal) * sizeof(int) + 4 * sizeof(float), stream);

    // --- CSR build + norm + edge-pair packing ---
    deg_hist_pairs_kernel<<<512, 256, 0, stream>>>(ei, nei, hist, cnt2, (int)Nal, pp, pn, E);
    merge_hist_kernel<<<(Nn + 255) / 256, 256, 0, stream>>>(hist, cnt2, (int)Nal,
                                                            dinv, rowptr, pg, Nn);
    scan_kernel<<<1, 1024, 0, stream>>>(rowptr, Nn);
    cursor_init_kernel<<<(Nn * 4 + 255) / 256, 256, 0, stream>>>(rowptr, pg, cursor, Nn * 4);
    fill_kernel<<<512, 256, 0, stream>>>(ei, dinv, cursor, colidx, wnorm, E);

    // --- conv1: XT = [x | segsum64(x)]; h = relu(XT @ W1cat + b1) ---
    xt_kernel<<<(Nn + 3) / 4, 256, 0, stream>>>(x, rowptr, colidx, wnorm, XT, Nn);
    gemm_mfma<<<dim3(5, MB), 256, 0, stream>>>(
        XT, 128, W1, nullptr, b1, nullptr, h, Nn, 128, 300, 300, 1);

    // --- conv2 fused: G2 = h @ [W2[0] | W2[1]] ---
    gemm_mfma<<<dim3(4, MB), 256, 0, stream>>>(
        h, 300, W2, W2 + 300 * 100, nullptr, nullptr, G2, Nn, 300, 200, 100, 0);
    // hWb = bf16(G2[:,100:200]); x1 = relu(G2[:,0:100] + segsum(hWb) + b2) fused
    pack_bf16_kernel<<<(Nn * 32 + 255) / 256, 256, 0, stream>>>(G2, 200, 100, 100, hWb, Nn);
    segsum_combine1_kernel<<<(Nn + 3) / 4, 256, 0, stream>>>(hWb, rowptr, colidx, wnorm,
                                                             G2, b2, x1, Nn);

    // --- skips fused: S = x @ [lw1|lw2] + [lb1|lb2]; xo = x1+relu(S0), zf = fp8(x1+relu(S1)) ---
    gemm_mfma<<<dim3(4, MB), 256, 0, stream>>>(
        x, 64, lw1, lw2, lb1, lb2, S, Nn, 64, 200, 100, 0);
    combine2_kernel<<<(Nn * 32 + 255) / 256, 256, 0, stream>>>(S, x1, xo, zf, Nn);

    // --- edge reconstruction losses (pos: y=0, neg: y=1), fp8 z, pipelined ---
    edge_loss_fp8_kernel<<<dim3(1024, 2), 256, 0, stream>>>(zf, pp, pn, E, acc);

    // --- conv3 (width 1): sv = xo@W3[1]; out = xo@W3[0] + segsum(sv) + b3 ---
    rowdot_kernel<<<(Nn + 255) / 256, 256, 0, stream>>>(xo, W3 + 100, sv, Nn);
    out_kernel<<<(Nn + 255) / 256, 256, 0, stream>>>(xo, W3, b3, rowptr, colidx, wnorm,
                                                     sv, (float*)d_out, Nn);

    finalize_kernel<<<1, 1, 0, stream>>>((float*)d_out, acc, c1, c2, Nn, E);
}

// Round 12
// 266.656 us; speedup vs baseline: 1.0294x; 1.0294x over previous
//
#include <hip/hip_runtime.h>
#include <math.h>

// ---------------------------------------------------------------------------
// Net_1503238553644: 2-layer ChebConv(K=2) GNN + linear skips + edge recon loss
// N=13627, E=504378, F=64, H1=300, H2=100, LIN=100
// R12: CSR build with ZERO global atomics — per-block LDS histograms (54.5KB)
//      + per-(block,node) offset table + LDS-rank fill. R11's global-atomic
//      rate floor (23 G ops/s) eliminated. MFMA GEMM + fp8 loss unchanged.
// ---------------------------------------------------------------------------

typedef unsigned short ushort_t;
typedef float v2f __attribute__((ext_vector_type(2)));
typedef short bf16x8 __attribute__((ext_vector_type(8)));
typedef float f32x4 __attribute__((ext_vector_type(4)));

#define GBM 64
#define GBN 64
#define GBK 32
#define LDK 72   // bf16 per LDS row: 144B, 16B-aligned, 2-way bank alias (free)
#define HB  256  // histogram blocks (1 per CU)
#define NMAX 13632

__device__ inline short f2bf(float f) {              // RNE float->bf16
    unsigned u = __float_as_uint(f);
    u += 0x7fff + ((u >> 16) & 1);
    return (short)(u >> 16);
}
__device__ inline float bflo(unsigned w) { return __uint_as_float(w << 16); }
__device__ inline float bfhi(unsigned w) { return __uint_as_float(w & 0xffff0000u); }

// Pass 1a: per-block LDS histogram by src -> degslice[b][v]; packs pp/pn.
__global__ __launch_bounds__(256) void hist_src_pairs_kernel(
    const int* __restrict__ ei, const int* __restrict__ nei,
    int* __restrict__ degslice, int2* __restrict__ pp, int2* __restrict__ pn,
    int Nn, int Nal, int E) {
    __shared__ int lh[NMAX];
    for (int i = threadIdx.x; i < Nn; i += 256) lh[i] = 0;
    __syncthreads();
    const int b = blockIdx.x;
    const int chunk = (E + HB - 1) / HB;
    const int e0 = b * chunk;
    const int e1 = (e0 + chunk < E) ? (e0 + chunk) : E;
    for (int e = e0 + threadIdx.x; e < e1; e += 256) {
        int s = ei[e], d = ei[E + e];
        atomicAdd(&lh[s], 1);
        pp[e] = make_int2(s, d);
        pn[e] = make_int2(nei[e], nei[E + e]);
    }
    __syncthreads();
    int* slice = degslice + (size_t)b * Nal;
    for (int i = threadIdx.x; i < Nn; i += 256) slice[i] = lh[i];
}

// Pass 1b: per-block LDS histogram by dst -> cntslice[b][v].
__global__ __launch_bounds__(256) void hist_dst_kernel(
    const int* __restrict__ ei, int* __restrict__ cntslice, int Nn, int Nal, int E) {
    __shared__ int lh[NMAX];
    for (int i = threadIdx.x; i < Nn; i += 256) lh[i] = 0;
    __syncthreads();
    const int b = blockIdx.x;
    const int chunk = (E + HB - 1) / HB;
    const int e0 = b * chunk;
    const int e1 = (e0 + chunk < E) ? (e0 + chunk) : E;
    for (int e = e0 + threadIdx.x; e < e1; e += 256) {
        atomicAdd(&lh[ei[E + e]], 1);
    }
    __syncthreads();
    int* slice = cntslice + (size_t)b * Nal;
    for (int i = threadIdx.x; i < Nn; i += 256) slice[i] = lh[i];
}

// Merge: dinv[v] from deg slices; off[b][v] = prefix of cnt over blocks;
// rowptr[v+1] = total cnt.
__global__ void merge_kernel(const int* __restrict__ degslice, const int* __restrict__ cntslice,
                             int* __restrict__ off, int Nal,
                             float* __restrict__ dinv, int* __restrict__ rowptr, int n) {
    int v = blockIdx.x * blockDim.x + threadIdx.x;
    if (v >= n) return;
    int d = 0;
    for (int b = 0; b < HB; ++b) d += degslice[(size_t)b * Nal + v];
    dinv[v] = (d > 0) ? (1.0f / sqrtf((float)d)) : 0.0f;
    int run = 0;
    for (int b = 0; b < HB; ++b) {
        off[(size_t)b * Nal + v] = run;
        run += cntslice[(size_t)b * Nal + v];
    }
    rowptr[v + 1] = run;
    if (v == 0) rowptr[0] = 0;
}

// single-block inclusive scan of rowptr[1..n]
__global__ void scan_kernel(int* __restrict__ rowptr, int n) {
    __shared__ int wsum[16];
    __shared__ int carry_s;
    if (threadIdx.x == 0) carry_s = 0;
    __syncthreads();
    int nchunk = (n + 1023) / 1024;
    int wid = threadIdx.x >> 6, lane = threadIdx.x & 63;
    for (int c = 0; c < nchunk; ++c) {
        int i = c * 1024 + threadIdx.x;
        int v = (i < n) ? rowptr[i + 1] : 0;
        int s = v;
        for (int off = 1; off < 64; off <<= 1) {
            int t = __shfl_up(s, off, 64);
            if (lane >= off) s += t;
        }
        if (lane == 63) wsum[wid] = s;
        __syncthreads();
        if (wid == 0 && lane < 16) {
            int wsv = wsum[lane];
            for (int off = 1; off < 16; off <<= 1) {
                int t = __shfl_up(wsv, off, 64);
                if (lane >= off) wsv += t;
            }
            wsum[lane] = wsv;
        }
        __syncthreads();
        int base = carry_s + (wid > 0 ? wsum[wid - 1] : 0);
        int inc = base + s;
        if (i < n) rowptr[i + 1] = inc;
        __syncthreads();
        if (threadIdx.x == 1023) carry_s = inc;
        __syncthreads();
    }
}

// Pass 2: fill CSR — rank via LDS returning atomic, slot computed, no global atomics.
__global__ __launch_bounds__(256) void fill_lds_kernel(
    const int* __restrict__ ei, const float* __restrict__ dinv,
    const int* __restrict__ rowptr, const int* __restrict__ off, int Nal,
    int* __restrict__ colidx, float* __restrict__ wnorm, int Nn, int E) {
    __shared__ int lh[NMAX];
    for (int i = threadIdx.x; i < Nn; i += 256) lh[i] = 0;
    __syncthreads();
    const int b = blockIdx.x;
    const int chunk = (E + HB - 1) / HB;
    const int e0 = b * chunk;
    const int e1 = (e0 + chunk < E) ? (e0 + chunk) : E;
    const int* boff = off + (size_t)b * Nal;
    for (int e = e0 + threadIdx.x; e < e1; e += 256) {
        int s = ei[e], d = ei[E + e];
        int rank = atomicAdd(&lh[d], 1);
        int slot = rowptr[d] + boff[d] + rank;
        colidx[slot] = s;
        wnorm[slot] = -dinv[s] * dinv[d];
    }
}

// XT[node] = [ x[node] (64) | segsum64(x)[node] (64) ] — one wave per node,
// 4 edges in flight (16-lane groups, float4/lane = full 64-f32 row).
__global__ void xt_kernel(const float* __restrict__ x, const int* __restrict__ rowptr,
                          const int* __restrict__ colidx, const float* __restrict__ wnorm,
                          float* __restrict__ XT, int n) {
    int node = (blockIdx.x * blockDim.x + threadIdx.x) >> 6;
    if (node >= n) return;
    int lane = threadIdx.x & 63;
    int grp = lane >> 4;
    int l = lane & 15;
    int j0 = rowptr[node], j1 = rowptr[node + 1];
    float4 a = {0, 0, 0, 0};
    for (int j = j0 + grp; j < j1; j += 4) {
        int c = colidx[j];
        float w = wnorm[j];
        float4 v = ((const float4*)(x + (size_t)c * 64))[l];
        a.x += w * v.x; a.y += w * v.y; a.z += w * v.z; a.w += w * v.w;
    }
#pragma unroll
    for (int off = 16; off <= 32; off <<= 1) {
        a.x += __shfl_xor(a.x, off, 64);
        a.y += __shfl_xor(a.y, off, 64);
        a.z += __shfl_xor(a.z, off, 64);
        a.w += __shfl_xor(a.w, off, 64);
    }
    if (grp == 0) {
        float4 xv = ((const float4*)(x + (size_t)node * 64))[l];
        *(float4*)&XT[(size_t)node * 128 + l * 4] = xv;
        *(float4*)&XT[(size_t)node * 128 + 64 + l * 4] = a;
    }
}

// C[Nrows x Ncols] = relu?( A @ Bcat + biascat ), bf16 MFMA 64x64x32.
__global__ __launch_bounds__(256) void gemm_mfma(
    const float* __restrict__ A, int lda,
    const float* __restrict__ B0, const float* __restrict__ B1,
    const float* __restrict__ bias0, const float* __restrict__ bias1,
    float* __restrict__ C, int Nrows, int K, int Ncols, int split, int relu) {
    __shared__ short As[GBM * LDK];   // [m][k] bf16
    __shared__ short Bs[GBN * LDK];   // [n][k] bf16 (B transposed)
    const int bm = blockIdx.y * GBM, bn = blockIdx.x * GBN;
    const int tid = threadIdx.x;
    const int w = tid >> 6, l = tid & 63;
    const int wm = (w >> 1) * 32, wn = (w & 1) * 32;
    const int lr = l & 15;
    const int kg = l >> 4;
    const int arow = tid >> 2, aseg = tid & 3;
    const int bcol = tid & 63, bk2 = (tid >> 6) * 2;
    const int ldb0 = split, ldb1 = Ncols - split;

    const int arowg = bm + arow;
    const int bcolg = bn + bcol;
    const float* Bsrc = (bcolg < split) ? (B0 + bcolg)
                       : ((bcolg < Ncols) ? (B1 + (bcolg - split)) : nullptr);
    const int ldb = (bcolg < split) ? ldb0 : ldb1;

    f32x4 acc00 = {0,0,0,0}, acc01 = {0,0,0,0}, acc10 = {0,0,0,0}, acc11 = {0,0,0,0};

    for (int k0 = 0; k0 < K; k0 += GBK) {
        {
            int kk = k0 + aseg * 8;
            bf16x8 v;
            if (arowg < Nrows && kk + 7 < K) {
                float4 f0 = *(const float4*)&A[(size_t)arowg * lda + kk];
                float4 f1 = *(const float4*)&A[(size_t)arowg * lda + kk + 4];
                v[0] = f2bf(f0.x); v[1] = f2bf(f0.y); v[2] = f2bf(f0.z); v[3] = f2bf(f0.w);
                v[4] = f2bf(f1.x); v[5] = f2bf(f1.y); v[6] = f2bf(f1.z); v[7] = f2bf(f1.w);
            } else {
#pragma unroll
                for (int i = 0; i < 8; ++i)
                    v[i] = (arowg < Nrows && kk + i < K)
                         ? f2bf(A[(size_t)arowg * lda + kk + i]) : (short)0;
            }
            *(bf16x8*)&As[arow * LDK + aseg * 8] = v;
        }
#pragma unroll
        for (int q = 0; q < 4; ++q) {
            int k = q * 8 + bk2;
            unsigned pw = 0u;
            if (Bsrc) {
                float f0 = (k0 + k < K) ? Bsrc[(size_t)(k0 + k) * ldb] : 0.0f;
                float f1 = (k0 + k + 1 < K) ? Bsrc[(size_t)(k0 + k + 1) * ldb] : 0.0f;
                pw = (unsigned)(unsigned short)f2bf(f0)
                   | ((unsigned)(unsigned short)f2bf(f1) << 16);
            }
            *(unsigned*)&Bs[bcol * LDK + k] = pw;
        }
        __syncthreads();
        bf16x8 a0 = *(const bf16x8*)&As[(wm + lr) * LDK + kg * 8];
        bf16x8 a1 = *(const bf16x8*)&As[(wm + 16 + lr) * LDK + kg * 8];
        bf16x8 b0 = *(const bf16x8*)&Bs[(wn + lr) * LDK + kg * 8];
        bf16x8 b1 = *(const bf16x8*)&Bs[(wn + 16 + lr) * LDK + kg * 8];
        acc00 = __builtin_amdgcn_mfma_f32_16x16x32_bf16(a0, b0, acc00, 0, 0, 0);
        acc01 = __builtin_amdgcn_mfma_f32_16x16x32_bf16(a0, b1, acc01, 0, 0, 0);
        acc10 = __builtin_amdgcn_mfma_f32_16x16x32_bf16(a1, b0, acc10, 0, 0, 0);
        acc11 = __builtin_amdgcn_mfma_f32_16x16x32_bf16(a1, b1, acc11, 0, 0, 0);
        __syncthreads();
    }
#pragma unroll
    for (int i = 0; i < 2; ++i) {
        int rbase = bm + wm + i * 16 + kg * 4;
#pragma unroll
        for (int j = 0; j < 2; ++j) {
            int col = bn + wn + j * 16 + lr;
            if (col >= Ncols) continue;
            float bv = (col < split) ? (bias0 ? bias0[col] : 0.0f)
                                     : (bias1 ? bias1[col - split] : 0.0f);
            f32x4 a = (i == 0) ? (j == 0 ? acc00 : acc01) : (j == 0 ? acc10 : acc11);
#pragma unroll
            for (int r = 0; r < 4; ++r) {
                int row = rbase + r;
                if (row < Nrows) {
                    float o = a[r] + bv;
                    if (relu) o = fmaxf(o, 0.0f);
                    C[(size_t)row * Ncols + col] = o;
                }
            }
        }
    }
}

// pack src[:, off:off+w] (f32, stride ld) -> dst bf16 rows padded to 128 (zeros)
__global__ void pack_bf16_kernel(const float* __restrict__ src, int ld, int off, int w,
                                 ushort_t* __restrict__ dst, int n) {
    int idx = blockIdx.x * blockDim.x + threadIdx.x;
    if (idx >= n * 32) return;
    int i = idx >> 5, q = idx & 31;
    uint2 p = {0u, 0u};
    if (q * 4 < w) {
        float4 v = *(const float4*)&src[(size_t)i * ld + off + q * 4];
        p.x = (unsigned)(unsigned short)f2bf(v.x) | ((unsigned)(unsigned short)f2bf(v.y) << 16);
        p.y = (unsigned)(unsigned short)f2bf(v.z) | ((unsigned)(unsigned short)f2bf(v.w) << 16);
    }
    *(uint2*)&dst[(size_t)i * 128 + q * 4] = p;
}

// t = segsum(hWb); x1 = relu(G2[:,0:100] + t + b2) — fused epilogue.
__global__ void segsum_combine1_kernel(const ushort_t* __restrict__ hb,
                                       const int* __restrict__ rowptr, const int* __restrict__ colidx,
                                       const float* __restrict__ wnorm,
                                       const float* __restrict__ G2, const float* __restrict__ b2,
                                       float* __restrict__ x1, int n) {
    int node = (blockIdx.x * blockDim.x + threadIdx.x) >> 6;
    if (node >= n) return;
    int lane = threadIdx.x & 63;
    int grp = lane >> 4;
    int l = lane & 15;
    int j0 = rowptr[node], j1 = rowptr[node + 1];
    float acc[8] = {};
    for (int j = j0 + grp; j < j1; j += 4) {
        int c = colidx[j];
        float w = wnorm[j];
        uint4 v = ((const uint4*)(hb + (size_t)c * 128))[l];
        acc[0] += w * bflo(v.x); acc[1] += w * bfhi(v.x);
        acc[2] += w * bflo(v.y); acc[3] += w * bfhi(v.y);
        acc[4] += w * bflo(v.z); acc[5] += w * bfhi(v.z);
        acc[6] += w * bflo(v.w); acc[7] += w * bfhi(v.w);
    }
#pragma unroll
    for (int k = 0; k < 8; ++k) {
        acc[k] += __shfl_xor(acc[k], 16, 64);
        acc[k] += __shfl_xor(acc[k], 32, 64);
    }
    if (grp == 0) {
        int f = l * 8;
        if (f < 100) {
            float4 g0 = *(const float4*)&G2[(size_t)node * 200 + f];
            float4 bv0 = *(const float4*)&b2[f];
            float4 o0;
            o0.x = fmaxf(g0.x + acc[0] + bv0.x, 0.0f);
            o0.y = fmaxf(g0.y + acc[1] + bv0.y, 0.0f);
            o0.z = fmaxf(g0.z + acc[2] + bv0.z, 0.0f);
            o0.w = fmaxf(g0.w + acc[3] + bv0.w, 0.0f);
            *(float4*)&x1[(size_t)node * 100 + f] = o0;
            if (f + 8 <= 100) {
                float4 g1 = *(const float4*)&G2[(size_t)node * 200 + f + 4];
                float4 bv1 = *(const float4*)&b2[f + 4];
                float4 o1;
                o1.x = fmaxf(g1.x + acc[4] + bv1.x, 0.0f);
                o1.y = fmaxf(g1.y + acc[5] + bv1.y, 0.0f);
                o1.z = fmaxf(g1.z + acc[6] + bv1.z, 0.0f);
                o1.w = fmaxf(g1.w + acc[7] + bv1.w, 0.0f);
                *(float4*)&x1[(size_t)node * 100 + f + 4] = o1;
            }
        }
    }
}

// xo = x1 + relu(S[:,0:100]) (f32); zf = fp8(x1 + relu(S[:,100:200]))
__global__ void combine2_kernel(const float* __restrict__ S, const float* __restrict__ x1,
                                float* __restrict__ xo, unsigned* __restrict__ zf, int n) {
    int idx = blockIdx.x * blockDim.x + threadIdx.x;
    if (idx >= n * 32) return;
    int i = idx >> 5, q = idx & 31;
    unsigned w = 0u;
    if (q < 25) {
        float4 s1 = *(const float4*)&S[(size_t)i * 200 + q * 4];
        float4 s2 = *(const float4*)&S[(size_t)i * 200 + 100 + q * 4];
        float4 xv = *(const float4*)&x1[(size_t)i * 100 + q * 4];
        float4 a, b;
        a.x = xv.x + fmaxf(s1.x, 0.0f); a.y = xv.y + fmaxf(s1.y, 0.0f);
        a.z = xv.z + fmaxf(s1.z, 0.0f); a.w = xv.w + fmaxf(s1.w, 0.0f);
        b.x = xv.x + fmaxf(s2.x, 0.0f); b.y = xv.y + fmaxf(s2.y, 0.0f);
        b.z = xv.z + fmaxf(s2.z, 0.0f); b.w = xv.w + fmaxf(s2.w, 0.0f);
        *(float4*)&xo[(size_t)i * 100 + q * 4] = a;
        w = (unsigned)__builtin_amdgcn_cvt_pk_fp8_f32(b.x, b.y, 0, false);
        w = (unsigned)__builtin_amdgcn_cvt_pk_fp8_f32(b.z, b.w, (int)w, true);
    }
    zf[(size_t)i * 32 + q] = w;
}

// fused pos/neg loss on fp8 z rows: 8 lanes/edge, uint4/lane = full 128B row.
__global__ __launch_bounds__(256) void edge_loss_fp8_kernel(
    const unsigned* __restrict__ zf, const int2* __restrict__ pp,
    const int2* __restrict__ pn, int E, float* __restrict__ accv) {
    const int y = blockIdx.y;
    const int2* __restrict__ pairs = y ? pn : pp;
    const int l = threadIdx.x & 7;
    const int g = (blockIdx.x * blockDim.x + threadIdx.x) >> 3;
    const int ng = (gridDim.x * blockDim.x) >> 3;
    float s = 0.0f;
    int niter = (g < E) ? ((E - 1 - g) / ng + 1) : 0;
    if (niter > 0) {
        int eclamp1 = (g + ng < E) ? (g + ng) : (E - 1);
        int2 p0 = pairs[g];
        int2 p1 = pairs[eclamp1];
        uint4 ra0 = *(const uint4*)&zf[(size_t)p0.x * 32 + l * 4];
        uint4 rb0 = *(const uint4*)&zf[(size_t)p0.y * 32 + l * 4];
        for (int t = 0; t < niter; ++t) {
            int e2 = g + (t + 2) * ng;
            e2 = (e2 < E) ? e2 : (E - 1);
            int2 p2 = pairs[e2];
            uint4 ra1 = *(const uint4*)&zf[(size_t)p1.x * 32 + l * 4];
            uint4 rb1 = *(const uint4*)&zf[(size_t)p1.y * 32 + l * 4];
            float dot = 0.0f;
            v2f fa, fb;
            fa = __builtin_amdgcn_cvt_pk_f32_fp8(ra0.x, false);
            fb = __builtin_amdgcn_cvt_pk_f32_fp8(rb0.x, false);
            dot += fa.x * fb.x + fa.y * fb.y;
            fa = __builtin_amdgcn_cvt_pk_f32_fp8(ra0.x, true);
            fb = __builtin_amdgcn_cvt_pk_f32_fp8(rb0.x, true);
            dot += fa.x * fb.x + fa.y * fb.y;
            fa = __builtin_amdgcn_cvt_pk_f32_fp8(ra0.y, false);
            fb = __builtin_amdgcn_cvt_pk_f32_fp8(rb0.y, false);
            dot += fa.x * fb.x + fa.y * fb.y;
            fa = __builtin_amdgcn_cvt_pk_f32_fp8(ra0.y, true);
            fb = __builtin_amdgcn_cvt_pk_f32_fp8(rb0.y, true);
            dot += fa.x * fb.x + fa.y * fb.y;
            fa = __builtin_amdgcn_cvt_pk_f32_fp8(ra0.z, false);
            fb = __builtin_amdgcn_cvt_pk_f32_fp8(rb0.z, false);
            dot += fa.x * fb.x + fa.y * fb.y;
            fa = __builtin_amdgcn_cvt_pk_f32_fp8(ra0.z, true);
            fb = __builtin_amdgcn_cvt_pk_f32_fp8(rb0.z, true);
            dot += fa.x * fb.x + fa.y * fb.y;
            fa = __builtin_amdgcn_cvt_pk_f32_fp8(ra0.w, false);
            fb = __builtin_amdgcn_cvt_pk_f32_fp8(rb0.w, false);
            dot += fa.x * fb.x + fa.y * fb.y;
            fa = __builtin_amdgcn_cvt_pk_f32_fp8(ra0.w, true);
            fb = __builtin_amdgcn_cvt_pk_f32_fp8(rb0.w, true);
            dot += fa.x * fb.x + fa.y * fb.y;
            dot += __shfl_xor(dot, 1, 8);
            dot += __shfl_xor(dot, 2, 8);
            dot += __shfl_xor(dot, 4, 8);
            if (l == 0) {
                float sg = 1.0f / (1.0f + expf(-dot));
                s += y ? logf(1.0f - sg + 1e-15f) : logf(sg + 1e-15f);
            }
            p1 = p2; ra0 = ra1; rb0 = rb1;
        }
    }
    __shared__ float red[256];
    red[threadIdx.x] = s;
    __syncthreads();
    for (int st = 128; st > 0; st >>= 1) {
        if (threadIdx.x < st) red[threadIdx.x] += red[threadIdx.x + st];
        __syncthreads();
    }
    if (threadIdx.x == 0) atomicAdd(&accv[y], red[0]);
}

// sv[i] = xo[i,:] @ w (100-dim)
__global__ void rowdot_kernel(const float* __restrict__ xo, const float* __restrict__ w,
                              float* __restrict__ s, int n) {
    int i = blockIdx.x * blockDim.x + threadIdx.x;
    if (i >= n) return;
    const float4* a = (const float4*)(xo + (size_t)i * 100);
    const float4* wv = (const float4*)w;
    float acc = 0.0f;
#pragma unroll
    for (int q = 0; q < 25; ++q) {
        float4 va = a[q], vw = wv[q];
        acc += va.x * vw.x + va.y * vw.y + va.z * vw.z + va.w * vw.w;
    }
    s[i] = acc;
}

// out[i] = xo[i,:]@W3[0] + b3 + sum_j wnorm[j]*sv[colidx[j]]
__global__ void out_kernel(const float* __restrict__ xo, const float* __restrict__ W3,
                           const float* __restrict__ b3, const int* __restrict__ rowptr,
                           const int* __restrict__ colidx, const float* __restrict__ wnorm,
                           const float* __restrict__ sv, float* __restrict__ out, int n) {
    int i = blockIdx.x * blockDim.x + threadIdx.x;
    if (i >= n) return;
    const float4* a = (const float4*)(xo + (size_t)i * 100);
    const float4* wv = (const float4*)W3;
    float acc = b3[0];
#pragma unroll
    for (int q = 0; q < 25; ++q) {
        float4 va = a[q], vw = wv[q];
        acc += va.x * vw.x + va.y * vw.y + va.z * vw.z + va.w * vw.w;
    }
    int j1 = rowptr[i + 1];
    for (int j = rowptr[i]; j < j1; ++j)
        acc += wnorm[j] * sv[colidx[j]];
    out[i] = acc;
}

__global__ void finalize_kernel(float* __restrict__ out, const float* __restrict__ acc,
                                const float* __restrict__ c1, const float* __restrict__ c2,
                                int Nn, int E) {
    out[Nn]     = -(acc[0] + acc[1]) / (float)E;
    out[Nn + 1] = c1[0];
    out[Nn + 2] = c2[0];
}

extern "C" void kernel_launch(void* const* d_in, const int* in_sizes, int n_in,
                              void* d_out, int out_size, void* d_ws, size_t ws_size,
                              hipStream_t stream) {
    (void)n_in; (void)out_size; (void)ws_size;
    const float* x   = (const float*)d_in[0];
    const int*   ei  = (const int*)d_in[1];
    const int*   nei = (const int*)d_in[2];
    const float* W1  = (const float*)d_in[3];
    const float* b1  = (const float*)d_in[4];
    const float* W2  = (const float*)d_in[5];
    const float* b2  = (const float*)d_in[6];
    const float* W3  = (const float*)d_in[7];
    const float* b3  = (const float*)d_in[8];
    const float* lw1 = (const float*)d_in[9];
    const float* lb1 = (const float*)d_in[10];
    const float* lw2 = (const float*)d_in[11];
    const float* lb2 = (const float*)d_in[12];
    const float* c1  = (const float*)d_in[13];
    const float* c2  = (const float*)d_in[14];

    const int Nn = in_sizes[0] / 64;   // 13627
    const int E  = in_sizes[1] / 2;    // 504378

    const size_t Nal = ((size_t)Nn + 5) & ~(size_t)3;   // >= N+1, mult of 4
    const size_t Eal = ((size_t)E + 3) & ~(size_t)3;

    float* ws       = (float*)d_ws;
    float* acc      = ws;                           // 4 floats
    float* dinv     = acc + 4;                      // Nal
    int*   rowptr   = (int*)(dinv + Nal);           // Nal (N+1 used)
    int*   colidx   = rowptr + Nal;                 // Eal
    float* wnorm    = (float*)(colidx + Eal);       // Eal
    int2*  pp       = (int2*)(wnorm + Eal);         // Eal int2
    int2*  pn       = pp + Eal;                     // Eal int2
    int*   degslice = (int*)(pn + Eal);             // HB*Nal
    int*   cntslice = degslice + (size_t)HB * Nal;  // HB*Nal
    int*   off      = cntslice + (size_t)HB * Nal;  // HB*Nal
    float* XT       = (float*)(off + (size_t)HB * Nal);  // N*128
    float* h        = XT + (size_t)Nn * 128;        // N*300 (alias S: N*200)
    float* G2       = h  + (size_t)Nn * 300;        // N*200
    float* x1       = G2 + (size_t)Nn * 200;        // N*100
    float* xo       = x1 + (size_t)Nn * 100;        // N*100
    size_t zoff     = (size_t)(xo + (size_t)Nn * 100 - ws);
    zoff = (zoff + 31) & ~(size_t)31;               // 128B align
    unsigned* zf    = (unsigned*)(ws + zoff);       // N*32 words (fp8 rows, 128B)
    size_t hoff     = zoff + (size_t)Nn * 32 + 63;
    hoff &= ~(size_t)63;                            // 256B align
    ushort_t* hWb   = (ushort_t*)(ws + hoff);       // N*128 bf16 (256B rows)
    float* sv       = ws + hoff + (size_t)Nn * 64;  // Nal
    float* S        = h;                            // alias (h dead after conv2 gemm)

    const int MB = (Nn + GBM - 1) / GBM;

    hipMemsetAsync(acc, 0, 4 * sizeof(float), stream);

    // --- CSR build, zero global atomics ---
    hist_src_pairs_kernel<<<HB, 256, 0, stream>>>(ei, nei, degslice, pp, pn, Nn, (int)Nal, E);
    hist_dst_kernel<<<HB, 256, 0, stream>>>(ei, cntslice, Nn, (int)Nal, E);
    merge_kernel<<<(Nn + 255) / 256, 256, 0, stream>>>(degslice, cntslice, off, (int)Nal,
                                                       dinv, rowptr, Nn);
    scan_kernel<<<1, 1024, 0, stream>>>(rowptr, Nn);
    fill_lds_kernel<<<HB, 256, 0, stream>>>(ei, dinv, rowptr, off, (int)Nal,
                                            colidx, wnorm, Nn, E);

    // --- conv1: XT = [x | segsum64(x)]; h = relu(XT @ W1cat + b1) ---
    xt_kernel<<<(Nn + 3) / 4, 256, 0, stream>>>(x, rowptr, colidx, wnorm, XT, Nn);
    gemm_mfma<<<dim3(5, MB), 256, 0, stream>>>(
        XT, 128, W1, nullptr, b1, nullptr, h, Nn, 128, 300, 300, 1);

    // --- conv2 fused: G2 = h @ [W2[0] | W2[1]] ---
    gemm_mfma<<<dim3(4, MB), 256, 0, stream>>>(
        h, 300, W2, W2 + 300 * 100, nullptr, nullptr, G2, Nn, 300, 200, 100, 0);
    // hWb = bf16(G2[:,100:200]); x1 = relu(G2[:,0:100] + segsum(hWb) + b2) fused
    pack_bf16_kernel<<<(Nn * 32 + 255) / 256, 256, 0, stream>>>(G2, 200, 100, 100, hWb, Nn);
    segsum_combine1_kernel<<<(Nn + 3) / 4, 256, 0, stream>>>(hWb, rowptr, colidx, wnorm,
                                                             G2, b2, x1, Nn);

    // --- skips fused: S = x @ [lw1|lw2] + [lb1|lb2]; xo = x1+relu(S0), zf = fp8(x1+relu(S1)) ---
    gemm_mfma<<<dim3(4, MB), 256, 0, stream>>>(
        x, 64, lw1, lw2, lb1, lb2, S, Nn, 64, 200, 100, 0);
    combine2_kernel<<<(Nn * 32 + 255) / 256, 256, 0, stream>>>(S, x1, xo, zf, Nn);

    // --- edge reconstruction losses (pos: y=0, neg: y=1), fp8 z, pipelined ---
    edge_loss_fp8_kernel<<<dim3(1024, 2), 256, 0, stream>>>(zf, pp, pn, E, acc);

    // --- conv3 (width 1): sv = xo@W3[1]; out = xo@W3[0] + segsum(sv) + b3 ---
    rowdot_kernel<<<(Nn + 255) / 256, 256, 0, stream>>>(xo, W3 + 100, sv, Nn);
    out_kernel<<<(Nn + 255) / 256, 256, 0, stream>>>(xo, W3, b3, rowptr, colidx, wnorm,
                                                     sv, (float*)d_out, Nn);

    finalize_kernel<<<1, 1, 0, stream>>>((float*)d_out, acc, c1, c2, Nn, E);
}

// Round 13
// 255.174 us; speedup vs baseline: 1.0757x; 1.0450x over previous
//
#include <hip/hip_runtime.h>
#include <math.h>

// ---------------------------------------------------------------------------
// Net_1503238553644: 2-layer ChebConv(K=2) GNN + linear skips + edge recon loss
// N=13627, E=504378, F=64, H1=300, H2=100, LIN=100
// R13: fused dual-LDS-histogram CSR build (HB=128, one edge pass, zero global
//      atomics); pack fused into conv2 GEMM epilogue (bf16 direct); rowdot
//      fused into combine2; finalize fused into out. 13 launches (was 17).
// ---------------------------------------------------------------------------

typedef unsigned short ushort_t;
typedef float v2f __attribute__((ext_vector_type(2)));
typedef short bf16x8 __attribute__((ext_vector_type(8)));
typedef float f32x4 __attribute__((ext_vector_type(4)));

#define GBM 64
#define GBN 64
#define GBK 32
#define LDK 72   // bf16 per LDS row: 144B, 16B-aligned, 2-way bank alias (free)
#define HB  128  // histogram blocks
#define NMAX 13632

__device__ inline short f2bf(float f) {              // RNE float->bf16
    unsigned u = __float_as_uint(f);
    u += 0x7fff + ((u >> 16) & 1);
    return (short)(u >> 16);
}
__device__ inline float bflo(unsigned w) { return __uint_as_float(w << 16); }
__device__ inline float bfhi(unsigned w) { return __uint_as_float(w & 0xffff0000u); }

// Pass 1: per-block dual LDS histograms (src + dst) in one edge pass; packs pp/pn.
__global__ __launch_bounds__(256) void hist_both_pairs_kernel(
    const int* __restrict__ ei, const int* __restrict__ nei,
    int* __restrict__ degslice, int* __restrict__ cntslice,
    int2* __restrict__ pp, int2* __restrict__ pn, int Nn, int Nal, int E) {
    __shared__ int lhs[NMAX];   // by src
    __shared__ int lhd[NMAX];   // by dst
    for (int i = threadIdx.x; i < Nn; i += 256) { lhs[i] = 0; lhd[i] = 0; }
    __syncthreads();
    const int b = blockIdx.x;
    const int chunk = (E + HB - 1) / HB;
    const int e0 = b * chunk;
    const int e1 = (e0 + chunk < E) ? (e0 + chunk) : E;
    for (int e = e0 + threadIdx.x; e < e1; e += 256) {
        int s = ei[e], d = ei[E + e];
        atomicAdd(&lhs[s], 1);
        atomicAdd(&lhd[d], 1);
        pp[e] = make_int2(s, d);
        pn[e] = make_int2(nei[e], nei[E + e]);
    }
    __syncthreads();
    int* ds = degslice + (size_t)b * Nal;
    int* cs = cntslice + (size_t)b * Nal;
    for (int i = threadIdx.x; i < Nn; i += 256) { ds[i] = lhs[i]; cs[i] = lhd[i]; }
}

// Merge: dinv[v]; off[b][v] = prefix of cnt over blocks; rowptr[v+1] = total.
__global__ void merge_kernel(const int* __restrict__ degslice, const int* __restrict__ cntslice,
                             int* __restrict__ off, int Nal,
                             float* __restrict__ dinv, int* __restrict__ rowptr, int n) {
    int v = blockIdx.x * blockDim.x + threadIdx.x;
    if (v < n) {
        int d = 0;
#pragma unroll 4
        for (int b = 0; b < HB; ++b) d += degslice[(size_t)b * Nal + v];
        dinv[v] = (d > 0) ? (1.0f / sqrtf((float)d)) : 0.0f;
        int run = 0;
        for (int b = 0; b < HB; ++b) {
            off[(size_t)b * Nal + v] = run;
            run += cntslice[(size_t)b * Nal + v];
        }
        rowptr[v + 1] = run;
    }
    if (v == 0) rowptr[0] = 0;
}

// single-block inclusive scan of rowptr[1..n]
__global__ void scan_kernel(int* __restrict__ rowptr, int n) {
    __shared__ int wsum[16];
    __shared__ int carry_s;
    if (threadIdx.x == 0) carry_s = 0;
    __syncthreads();
    int nchunk = (n + 1023) / 1024;
    int wid = threadIdx.x >> 6, lane = threadIdx.x & 63;
    for (int c = 0; c < nchunk; ++c) {
        int i = c * 1024 + threadIdx.x;
        int v = (i < n) ? rowptr[i + 1] : 0;
        int s = v;
        for (int off = 1; off < 64; off <<= 1) {
            int t = __shfl_up(s, off, 64);
            if (lane >= off) s += t;
        }
        if (lane == 63) wsum[wid] = s;
        __syncthreads();
        if (wid == 0 && lane < 16) {
            int wsv = wsum[lane];
            for (int off = 1; off < 16; off <<= 1) {
                int t = __shfl_up(wsv, off, 64);
                if (lane >= off) wsv += t;
            }
            wsum[lane] = wsv;
        }
        __syncthreads();
        int base = carry_s + (wid > 0 ? wsum[wid - 1] : 0);
        int inc = base + s;
        if (i < n) rowptr[i + 1] = inc;
        __syncthreads();
        if (threadIdx.x == 1023) carry_s = inc;
        __syncthreads();
    }
}

// Pass 2: fill CSR — rank via LDS returning atomic, slot computed, no global atomics.
__global__ __launch_bounds__(256) void fill_lds_kernel(
    const int* __restrict__ ei, const float* __restrict__ dinv,
    const int* __restrict__ rowptr, const int* __restrict__ off, int Nal,
    int* __restrict__ colidx, float* __restrict__ wnorm, int Nn, int E) {
    __shared__ int lh[NMAX];
    for (int i = threadIdx.x; i < Nn; i += 256) lh[i] = 0;
    __syncthreads();
    const int b = blockIdx.x;
    const int chunk = (E + HB - 1) / HB;
    const int e0 = b * chunk;
    const int e1 = (e0 + chunk < E) ? (e0 + chunk) : E;
    const int* boff = off + (size_t)b * Nal;
    for (int e = e0 + threadIdx.x; e < e1; e += 256) {
        int s = ei[e], d = ei[E + e];
        int rank = atomicAdd(&lh[d], 1);
        int slot = rowptr[d] + boff[d] + rank;
        colidx[slot] = s;
        wnorm[slot] = -dinv[s] * dinv[d];
    }
}

// XT[node] = [ x[node] (64) | segsum64(x)[node] (64) ] — one wave per node,
// 4 edges in flight (16-lane groups, float4/lane = full 64-f32 row).
__global__ void xt_kernel(const float* __restrict__ x, const int* __restrict__ rowptr,
                          const int* __restrict__ colidx, const float* __restrict__ wnorm,
                          float* __restrict__ XT, int n) {
    int node = (blockIdx.x * blockDim.x + threadIdx.x) >> 6;
    if (node >= n) return;
    int lane = threadIdx.x & 63;
    int grp = lane >> 4;
    int l = lane & 15;
    int j0 = rowptr[node], j1 = rowptr[node + 1];
    float4 a = {0, 0, 0, 0};
    for (int j = j0 + grp; j < j1; j += 4) {
        int c = colidx[j];
        float w = wnorm[j];
        float4 v = ((const float4*)(x + (size_t)c * 64))[l];
        a.x += w * v.x; a.y += w * v.y; a.z += w * v.z; a.w += w * v.w;
    }
#pragma unroll
    for (int off = 16; off <= 32; off <<= 1) {
        a.x += __shfl_xor(a.x, off, 64);
        a.y += __shfl_xor(a.y, off, 64);
        a.z += __shfl_xor(a.z, off, 64);
        a.w += __shfl_xor(a.w, off, 64);
    }
    if (grp == 0) {
        float4 xv = ((const float4*)(x + (size_t)node * 64))[l];
        *(float4*)&XT[(size_t)node * 128 + l * 4] = xv;
        *(float4*)&XT[(size_t)node * 128 + 64 + l * 4] = a;
    }
}

// C = relu?( A @ Bcat + biascat ), bf16 MFMA 64x64x32.
// cols < split -> C[row*ldc + col]; cols >= split -> Cbf (bf16, rows of 128)
// if Cbf != nullptr, else C[row*ldc + col].
__global__ __launch_bounds__(256) void gemm_mfma(
    const float* __restrict__ A, int lda,
    const float* __restrict__ B0, const float* __restrict__ B1,
    const float* __restrict__ bias0, const float* __restrict__ bias1,
    float* __restrict__ C, int ldc, ushort_t* __restrict__ Cbf,
    int Nrows, int K, int Ncols, int split, int relu) {
    __shared__ short As[GBM * LDK];   // [m][k] bf16
    __shared__ short Bs[GBN * LDK];   // [n][k] bf16 (B transposed)
    const int bm = blockIdx.y * GBM, bn = blockIdx.x * GBN;
    const int tid = threadIdx.x;
    const int w = tid >> 6, l = tid & 63;
    const int wm = (w >> 1) * 32, wn = (w & 1) * 32;
    const int lr = l & 15;
    const int kg = l >> 4;
    const int arow = tid >> 2, aseg = tid & 3;
    const int bcol = tid & 63, bk2 = (tid >> 6) * 2;
    const int ldb0 = split, ldb1 = Ncols - split;

    const int arowg = bm + arow;
    const int bcolg = bn + bcol;
    const float* Bsrc = (bcolg < split) ? (B0 + bcolg)
                       : ((bcolg < Ncols) ? (B1 + (bcolg - split)) : nullptr);
    const int ldb = (bcolg < split) ? ldb0 : ldb1;

    f32x4 acc00 = {0,0,0,0}, acc01 = {0,0,0,0}, acc10 = {0,0,0,0}, acc11 = {0,0,0,0};

    for (int k0 = 0; k0 < K; k0 += GBK) {
        {
            int kk = k0 + aseg * 8;
            bf16x8 v;
            if (arowg < Nrows && kk + 7 < K) {
                float4 f0 = *(const float4*)&A[(size_t)arowg * lda + kk];
                float4 f1 = *(const float4*)&A[(size_t)arowg * lda + kk + 4];
                v[0] = f2bf(f0.x); v[1] = f2bf(f0.y); v[2] = f2bf(f0.z); v[3] = f2bf(f0.w);
                v[4] = f2bf(f1.x); v[5] = f2bf(f1.y); v[6] = f2bf(f1.z); v[7] = f2bf(f1.w);
            } else {
#pragma unroll
                for (int i = 0; i < 8; ++i)
                    v[i] = (arowg < Nrows && kk + i < K)
                         ? f2bf(A[(size_t)arowg * lda + kk + i]) : (short)0;
            }
            *(bf16x8*)&As[arow * LDK + aseg * 8] = v;
        }
#pragma unroll
        for (int q = 0; q < 4; ++q) {
            int k = q * 8 + bk2;
            unsigned pw = 0u;
            if (Bsrc) {
                float f0 = (k0 + k < K) ? Bsrc[(size_t)(k0 + k) * ldb] : 0.0f;
                float f1 = (k0 + k + 1 < K) ? Bsrc[(size_t)(k0 + k + 1) * ldb] : 0.0f;
                pw = (unsigned)(unsigned short)f2bf(f0)
                   | ((unsigned)(unsigned short)f2bf(f1) << 16);
            }
            *(unsigned*)&Bs[bcol * LDK + k] = pw;
        }
        __syncthreads();
        bf16x8 a0 = *(const bf16x8*)&As[(wm + lr) * LDK + kg * 8];
        bf16x8 a1 = *(const bf16x8*)&As[(wm + 16 + lr) * LDK + kg * 8];
        bf16x8 b0 = *(const bf16x8*)&Bs[(wn + lr) * LDK + kg * 8];
        bf16x8 b1 = *(const bf16x8*)&Bs[(wn + 16 + lr) * LDK + kg * 8];
        acc00 = __builtin_amdgcn_mfma_f32_16x16x32_bf16(a0, b0, acc00, 0, 0, 0);
        acc01 = __builtin_amdgcn_mfma_f32_16x16x32_bf16(a0, b1, acc01, 0, 0, 0);
        acc10 = __builtin_amdgcn_mfma_f32_16x16x32_bf16(a1, b0, acc10, 0, 0, 0);
        acc11 = __builtin_amdgcn_mfma_f32_16x16x32_bf16(a1, b1, acc11, 0, 0, 0);
        __syncthreads();
    }
#pragma unroll
    for (int i = 0; i < 2; ++i) {
        int rbase = bm + wm + i * 16 + kg * 4;
#pragma unroll
        for (int j = 0; j < 2; ++j) {
            int col = bn + wn + j * 16 + lr;
            if (col >= Ncols) continue;
            float bv = (col < split) ? (bias0 ? bias0[col] : 0.0f)
                                     : (bias1 ? bias1[col - split] : 0.0f);
            f32x4 a = (i == 0) ? (j == 0 ? acc00 : acc01) : (j == 0 ? acc10 : acc11);
#pragma unroll
            for (int r = 0; r < 4; ++r) {
                int row = rbase + r;
                if (row >= Nrows) continue;
                float o = a[r] + bv;
                if (relu) o = fmaxf(o, 0.0f);
                if (col < split || !Cbf)
                    C[(size_t)row * ldc + col] = o;
                else
                    Cbf[(size_t)row * 128 + (col - split)] = (ushort_t)f2bf(o);
            }
        }
    }
}

// t = segsum(hWb); x1 = relu(G2a + t + b2) — fused epilogue. G2a is N x 100.
__global__ void segsum_combine1_kernel(const ushort_t* __restrict__ hb,
                                       const int* __restrict__ rowptr, const int* __restrict__ colidx,
                                       const float* __restrict__ wnorm,
                                       const float* __restrict__ G2a, const float* __restrict__ b2,
                                       float* __restrict__ x1, int n) {
    int node = (blockIdx.x * blockDim.x + threadIdx.x) >> 6;
    if (node >= n) return;
    int lane = threadIdx.x & 63;
    int grp = lane >> 4;
    int l = lane & 15;
    int j0 = rowptr[node], j1 = rowptr[node + 1];
    float acc[8] = {};
    for (int j = j0 + grp; j < j1; j += 4) {
        int c = colidx[j];
        float w = wnorm[j];
        uint4 v = ((const uint4*)(hb + (size_t)c * 128))[l];
        acc[0] += w * bflo(v.x); acc[1] += w * bfhi(v.x);
        acc[2] += w * bflo(v.y); acc[3] += w * bfhi(v.y);
        acc[4] += w * bflo(v.z); acc[5] += w * bfhi(v.z);
        acc[6] += w * bflo(v.w); acc[7] += w * bfhi(v.w);
    }
#pragma unroll
    for (int k = 0; k < 8; ++k) {
        acc[k] += __shfl_xor(acc[k], 16, 64);
        acc[k] += __shfl_xor(acc[k], 32, 64);
    }
    if (grp == 0) {
        int f = l * 8;
        if (f < 100) {
            float4 g0 = *(const float4*)&G2a[(size_t)node * 100 + f];
            float4 bv0 = *(const float4*)&b2[f];
            float4 o0;
            o0.x = fmaxf(g0.x + acc[0] + bv0.x, 0.0f);
            o0.y = fmaxf(g0.y + acc[1] + bv0.y, 0.0f);
            o0.z = fmaxf(g0.z + acc[2] + bv0.z, 0.0f);
            o0.w = fmaxf(g0.w + acc[3] + bv0.w, 0.0f);
            *(float4*)&x1[(size_t)node * 100 + f] = o0;
            if (f + 8 <= 100) {
                float4 g1 = *(const float4*)&G2a[(size_t)node * 100 + f + 4];
                float4 bv1 = *(const float4*)&b2[f + 4];
                float4 o1;
                o1.x = fmaxf(g1.x + acc[4] + bv1.x, 0.0f);
                o1.y = fmaxf(g1.y + acc[5] + bv1.y, 0.0f);
                o1.z = fmaxf(g1.z + acc[6] + bv1.z, 0.0f);
                o1.w = fmaxf(g1.w + acc[7] + bv1.w, 0.0f);
                *(float4*)&x1[(size_t)node * 100 + f + 4] = o1;
            }
        }
    }
}

// xo = x1 + relu(S[:,0:100]); zf = fp8(x1 + relu(S[:,100:200]));
// sv[i] = xo[i,:] @ w3b (fused rowdot via 32-lane shfl reduce).
__global__ void combine2_kernel(const float* __restrict__ S, const float* __restrict__ x1,
                                const float* __restrict__ w3b,
                                float* __restrict__ xo, unsigned* __restrict__ zf,
                                float* __restrict__ sv, int n) {
    int idx = blockIdx.x * blockDim.x + threadIdx.x;
    if (idx >= n * 32) return;
    int i = idx >> 5, q = idx & 31;
    unsigned w = 0u;
    float part = 0.0f;
    if (q < 25) {
        float4 s1 = *(const float4*)&S[(size_t)i * 200 + q * 4];
        float4 s2 = *(const float4*)&S[(size_t)i * 200 + 100 + q * 4];
        float4 xv = *(const float4*)&x1[(size_t)i * 100 + q * 4];
        float4 a, b;
        a.x = xv.x + fmaxf(s1.x, 0.0f); a.y = xv.y + fmaxf(s1.y, 0.0f);
        a.z = xv.z + fmaxf(s1.z, 0.0f); a.w = xv.w + fmaxf(s1.w, 0.0f);
        b.x = xv.x + fmaxf(s2.x, 0.0f); b.y = xv.y + fmaxf(s2.y, 0.0f);
        b.z = xv.z + fmaxf(s2.z, 0.0f); b.w = xv.w + fmaxf(s2.w, 0.0f);
        *(float4*)&xo[(size_t)i * 100 + q * 4] = a;
        w = (unsigned)__builtin_amdgcn_cvt_pk_fp8_f32(b.x, b.y, 0, false);
        w = (unsigned)__builtin_amdgcn_cvt_pk_fp8_f32(b.z, b.w, (int)w, true);
        float4 wv = *(const float4*)&w3b[q * 4];
        part = a.x * wv.x + a.y * wv.y + a.z * wv.z + a.w * wv.w;
    }
    zf[(size_t)i * 32 + q] = w;
#pragma unroll
    for (int off = 16; off > 0; off >>= 1)
        part += __shfl_xor(part, off, 32);
    if (q == 0) sv[i] = part;
}

// fused pos/neg loss on fp8 z rows: 8 lanes/edge, uint4/lane = full 128B row.
__global__ __launch_bounds__(256) void edge_loss_fp8_kernel(
    const unsigned* __restrict__ zf, const int2* __restrict__ pp,
    const int2* __restrict__ pn, int E, float* __restrict__ accv) {
    const int y = blockIdx.y;
    const int2* __restrict__ pairs = y ? pn : pp;
    const int l = threadIdx.x & 7;
    const int g = (blockIdx.x * blockDim.x + threadIdx.x) >> 3;
    const int ng = (gridDim.x * blockDim.x) >> 3;
    float s = 0.0f;
    int niter = (g < E) ? ((E - 1 - g) / ng + 1) : 0;
    if (niter > 0) {
        int eclamp1 = (g + ng < E) ? (g + ng) : (E - 1);
        int2 p0 = pairs[g];
        int2 p1 = pairs[eclamp1];
        uint4 ra0 = *(const uint4*)&zf[(size_t)p0.x * 32 + l * 4];
        uint4 rb0 = *(const uint4*)&zf[(size_t)p0.y * 32 + l * 4];
        for (int t = 0; t < niter; ++t) {
            int e2 = g + (t + 2) * ng;
            e2 = (e2 < E) ? e2 : (E - 1);
            int2 p2 = pairs[e2];
            uint4 ra1 = *(const uint4*)&zf[(size_t)p1.x * 32 + l * 4];
            uint4 rb1 = *(const uint4*)&zf[(size_t)p1.y * 32 + l * 4];
            float dot = 0.0f;
            v2f fa, fb;
            fa = __builtin_amdgcn_cvt_pk_f32_fp8(ra0.x, false);
            fb = __builtin_amdgcn_cvt_pk_f32_fp8(rb0.x, false);
            dot += fa.x * fb.x + fa.y * fb.y;
            fa = __builtin_amdgcn_cvt_pk_f32_fp8(ra0.x, true);
            fb = __builtin_amdgcn_cvt_pk_f32_fp8(rb0.x, true);
            dot += fa.x * fb.x + fa.y * fb.y;
            fa = __builtin_amdgcn_cvt_pk_f32_fp8(ra0.y, false);
            fb = __builtin_amdgcn_cvt_pk_f32_fp8(rb0.y, false);
            dot += fa.x * fb.x + fa.y * fb.y;
            fa = __builtin_amdgcn_cvt_pk_f32_fp8(ra0.y, true);
            fb = __builtin_amdgcn_cvt_pk_f32_fp8(rb0.y, true);
            dot += fa.x * fb.x + fa.y * fb.y;
            fa = __builtin_amdgcn_cvt_pk_f32_fp8(ra0.z, false);
            fb = __builtin_amdgcn_cvt_pk_f32_fp8(rb0.z, false);
            dot += fa.x * fb.x + fa.y * fb.y;
            fa = __builtin_amdgcn_cvt_pk_f32_fp8(ra0.z, true);
            fb = __builtin_amdgcn_cvt_pk_f32_fp8(rb0.z, true);
            dot += fa.x * fb.x + fa.y * fb.y;
            fa = __builtin_amdgcn_cvt_pk_f32_fp8(ra0.w, false);
            fb = __builtin_amdgcn_cvt_pk_f32_fp8(rb0.w, false);
            dot += fa.x * fb.x + fa.y * fb.y;
            fa = __builtin_amdgcn_cvt_pk_f32_fp8(ra0.w, true);
            fb = __builtin_amdgcn_cvt_pk_f32_fp8(rb0.w, true);
            dot += fa.x * fb.x + fa.y * fb.y;
            dot += __shfl_xor(dot, 1, 8);
            dot += __shfl_xor(dot, 2, 8);
            dot += __shfl_xor(dot, 4, 8);
            if (l == 0) {
                float sg = 1.0f / (1.0f + expf(-dot));
                s += y ? logf(1.0f - sg + 1e-15f) : logf(sg + 1e-15f);
            }
            p1 = p2; ra0 = ra1; rb0 = rb1;
        }
    }
    __shared__ float red[256];
    red[threadIdx.x] = s;
    __syncthreads();
    for (int st = 128; st > 0; st >>= 1) {
        if (threadIdx.x < st) red[threadIdx.x] += red[threadIdx.x + st];
        __syncthreads();
    }
    if (threadIdx.x == 0) atomicAdd(&accv[y], red[0]);
}

// out[i] = xo[i,:]@W3[0] + b3 + sum_j wnorm[j]*sv[colidx[j]]; thread 0 also
// writes r_loss/c1/c2 tail (acc is final: edge_loss precedes on stream).
__global__ void out_finalize_kernel(const float* __restrict__ xo, const float* __restrict__ W3,
                                    const float* __restrict__ b3, const int* __restrict__ rowptr,
                                    const int* __restrict__ colidx, const float* __restrict__ wnorm,
                                    const float* __restrict__ sv, const float* __restrict__ accv,
                                    const float* __restrict__ c1, const float* __restrict__ c2,
                                    float* __restrict__ out, int n, int E) {
    int i = blockIdx.x * blockDim.x + threadIdx.x;
    if (i == 0) {
        out[n]     = -(accv[0] + accv[1]) / (float)E;
        out[n + 1] = c1[0];
        out[n + 2] = c2[0];
    }
    if (i >= n) return;
    const float4* a = (const float4*)(xo + (size_t)i * 100);
    const float4* wv = (const float4*)W3;
    float acc = b3[0];
#pragma unroll
    for (int q = 0; q < 25; ++q) {
        float4 va = a[q], vw = wv[q];
        acc += va.x * vw.x + va.y * vw.y + va.z * vw.z + va.w * vw.w;
    }
    int j1 = rowptr[i + 1];
    for (int j = rowptr[i]; j < j1; ++j)
        acc += wnorm[j] * sv[colidx[j]];
    out[i] = acc;
}

extern "C" void kernel_launch(void* const* d_in, const int* in_sizes, int n_in,
                              void* d_out, int out_size, void* d_ws, size_t ws_size,
                              hipStream_t stream) {
    (void)n_in; (void)out_size; (void)ws_size;
    const float* x   = (const float*)d_in[0];
    const int*   ei  = (const int*)d_in[1];
    const int*   nei = (const int*)d_in[2];
    const float* W1  = (const float*)d_in[3];
    const float* b1  = (const float*)d_in[4];
    const float* W2  = (const float*)d_in[5];
    const float* b2  = (const float*)d_in[6];
    const float* W3  = (const float*)d_in[7];
    const float* b3  = (const float*)d_in[8];
    const float* lw1 = (const float*)d_in[9];
    const float* lb1 = (const float*)d_in[10];
    const float* lw2 = (const float*)d_in[11];
    const float* lb2 = (const float*)d_in[12];
    const float* c1  = (const float*)d_in[13];
    const float* c2  = (const float*)d_in[14];

    const int Nn = in_sizes[0] / 64;   // 13627
    const int E  = in_sizes[1] / 2;    // 504378

    const size_t Nal = ((size_t)Nn + 5) & ~(size_t)3;   // >= N+1, mult of 4
    const size_t Eal = ((size_t)E + 3) & ~(size_t)3;

    float* ws       = (float*)d_ws;
    float* acc      = ws;                           // 4 floats
    float* dinv     = acc + 4;                      // Nal
    int*   rowptr   = (int*)(dinv + Nal);           // Nal (N+1 used)
    int*   colidx   = rowptr + Nal;                 // Eal
    float* wnorm    = (float*)(colidx + Eal);       // Eal
    int2*  pp       = (int2*)(wnorm + Eal);         // Eal int2
    int2*  pn       = pp + Eal;                     // Eal int2
    int*   degslice = (int*)(pn + Eal);             // HB*Nal
    int*   cntslice = degslice + (size_t)HB * Nal;  // HB*Nal
    int*   off      = cntslice + (size_t)HB * Nal;  // HB*Nal
    float* XT       = (float*)(off + (size_t)HB * Nal);  // N*128
    float* h        = XT + (size_t)Nn * 128;        // N*300 (alias S: N*200)
    float* G2a      = h  + (size_t)Nn * 300;        // N*100
    float* x1       = G2a + (size_t)Nn * 100;       // N*100
    float* xo       = x1 + (size_t)Nn * 100;        // N*100
    size_t zoff     = (size_t)(xo + (size_t)Nn * 100 - ws);
    zoff = (zoff + 31) & ~(size_t)31;               // 128B align
    unsigned* zf    = (unsigned*)(ws + zoff);       // N*32 words (fp8 rows, 128B)
    size_t hoff     = zoff + (size_t)Nn * 32 + 63;
    hoff &= ~(size_t)63;                            // 256B align
    ushort_t* hWb   = (ushort_t*)(ws + hoff);       // N*128 bf16 (256B rows)
    float* sv       = ws + hoff + (size_t)Nn * 64;  // Nal
    float* S        = h;                            // alias (h dead after conv2 gemm)

    const int MB = (Nn + GBM - 1) / GBM;

    hipMemsetAsync(acc, 0, 4 * sizeof(float), stream);

    // --- CSR build, zero global atomics, one edge pass for both histograms ---
    hist_both_pairs_kernel<<<HB, 256, 0, stream>>>(ei, nei, degslice, cntslice,
                                                   pp, pn, Nn, (int)Nal, E);
    merge_kernel<<<(Nn + 255) / 256, 256, 0, stream>>>(degslice, cntslice, off, (int)Nal,
                                                       dinv, rowptr, Nn);
    scan_kernel<<<1, 1024, 0, stream>>>(rowptr, Nn);
    fill_lds_kernel<<<HB, 256, 0, stream>>>(ei, dinv, rowptr, off, (int)Nal,
                                            colidx, wnorm, Nn, E);

    // --- conv1: XT = [x | segsum64(x)]; h = relu(XT @ W1cat + b1) ---
    xt_kernel<<<(Nn + 3) / 4, 256, 0, stream>>>(x, rowptr, colidx, wnorm, XT, Nn);
    gemm_mfma<<<dim3(5, MB), 256, 0, stream>>>(
        XT, 128, W1, nullptr, b1, nullptr, h, 300, nullptr, Nn, 128, 300, 300, 1);

    // --- conv2 fused: [G2a | hWb(bf16)] = h @ [W2[0] | W2[1]] (pack fused) ---
    gemm_mfma<<<dim3(4, MB), 256, 0, stream>>>(
        h, 300, W2, W2 + 300 * 100, nullptr, nullptr, G2a, 100, hWb, Nn, 300, 200, 100, 0);
    // x1 = relu(G2a + segsum(hWb) + b2) fused
    segsum_combine1_kernel<<<(Nn + 3) / 4, 256, 0, stream>>>(hWb, rowptr, colidx, wnorm,
                                                             G2a, b2, x1, Nn);

    // --- skips fused: S = x @ [lw1|lw2] + [lb1|lb2];
    //     combine2: xo = x1+relu(S0), zf = fp8(x1+relu(S1)), sv = xo@W3[1] ---
    gemm_mfma<<<dim3(4, MB), 256, 0, stream>>>(
        x, 64, lw1, lw2, lb1, lb2, S, 200, nullptr, Nn, 64, 200, 100, 0);
    combine2_kernel<<<(Nn * 32 + 255) / 256, 256, 0, stream>>>(S, x1, W3 + 100,
                                                               xo, zf, sv, Nn);

    // --- edge reconstruction losses (pos: y=0, neg: y=1), fp8 z, pipelined ---
    edge_loss_fp8_kernel<<<dim3(1024, 2), 256, 0, stream>>>(zf, pp, pn, E, acc);

    // --- conv3 (width 1) + finalize: out = xo@W3[0] + segsum(sv) + b3; tail ---
    out_finalize_kernel<<<(Nn + 255) / 256, 256, 0, stream>>>(
        xo, W3, b3, rowptr, colidx, wnorm, sv, acc, c1, c2, (float*)d_out, Nn, E);
}

// Round 14
// 240.306 us; speedup vs baseline: 1.1423x; 1.0619x over previous
//
#include <hip/hip_runtime.h>
#include <math.h>

// ---------------------------------------------------------------------------
// Net_1503238553644: 2-layer ChebConv(K=2) GNN + linear skips + edge recon loss
// N=13627, E=504378, F=64, H1=300, H2=100, LIN=100
// R14: packed 16-bit LDS histograms (HB=256, 512-thr blocks, all CUs), ushort
//      off table, acc-zero folded into merge (no memset dispatch); depth-1 row
//      pipeline in xt/segsum gathers; edge_loss 2 independent streams/group.
// ---------------------------------------------------------------------------

typedef unsigned short ushort_t;
typedef float v2f __attribute__((ext_vector_type(2)));
typedef short bf16x8 __attribute__((ext_vector_type(8)));
typedef float f32x4 __attribute__((ext_vector_type(4)));

#define GBM 64
#define GBN 64
#define GBK 32
#define LDK 72    // bf16 per LDS row: 144B, 16B-aligned, 2-way bank alias (free)
#define HB  256   // histogram blocks (all CUs)
#define PACKN 6816  // ceil(13632/2) packed histogram words

__device__ inline short f2bf(float f) {              // RNE float->bf16
    unsigned u = __float_as_uint(f);
    u += 0x7fff + ((u >> 16) & 1);
    return (short)(u >> 16);
}
__device__ inline float bflo(unsigned w) { return __uint_as_float(w << 16); }
__device__ inline float bfhi(unsigned w) { return __uint_as_float(w & 0xffff0000u); }

// fp8x16 dot (two 128-bit regs = 16 e4m3 each), HW cvt_pk decode
__device__ inline float dot16fp8(uint4 ra, uint4 rb) {
    float dot = 0.0f;
    v2f fa, fb;
    fa = __builtin_amdgcn_cvt_pk_f32_fp8(ra.x, false);
    fb = __builtin_amdgcn_cvt_pk_f32_fp8(rb.x, false);
    dot += fa.x * fb.x + fa.y * fb.y;
    fa = __builtin_amdgcn_cvt_pk_f32_fp8(ra.x, true);
    fb = __builtin_amdgcn_cvt_pk_f32_fp8(rb.x, true);
    dot += fa.x * fb.x + fa.y * fb.y;
    fa = __builtin_amdgcn_cvt_pk_f32_fp8(ra.y, false);
    fb = __builtin_amdgcn_cvt_pk_f32_fp8(rb.y, false);
    dot += fa.x * fb.x + fa.y * fb.y;
    fa = __builtin_amdgcn_cvt_pk_f32_fp8(ra.y, true);
    fb = __builtin_amdgcn_cvt_pk_f32_fp8(rb.y, true);
    dot += fa.x * fb.x + fa.y * fb.y;
    fa = __builtin_amdgcn_cvt_pk_f32_fp8(ra.z, false);
    fb = __builtin_amdgcn_cvt_pk_f32_fp8(rb.z, false);
    dot += fa.x * fb.x + fa.y * fb.y;
    fa = __builtin_amdgcn_cvt_pk_f32_fp8(ra.z, true);
    fb = __builtin_amdgcn_cvt_pk_f32_fp8(rb.z, true);
    dot += fa.x * fb.x + fa.y * fb.y;
    fa = __builtin_amdgcn_cvt_pk_f32_fp8(ra.w, false);
    fb = __builtin_amdgcn_cvt_pk_f32_fp8(rb.w, false);
    dot += fa.x * fb.x + fa.y * fb.y;
    fa = __builtin_amdgcn_cvt_pk_f32_fp8(ra.w, true);
    fb = __builtin_amdgcn_cvt_pk_f32_fp8(rb.w, true);
    dot += fa.x * fb.x + fa.y * fb.y;
    return dot;
}

// Pass 1: packed dual LDS histograms (src + dst) in one edge pass; packs pp/pn.
__global__ __launch_bounds__(512) void hist_both_pairs_kernel(
    const int* __restrict__ ei, const int* __restrict__ nei,
    int* __restrict__ degp, int* __restrict__ cntp,
    int2* __restrict__ pp, int2* __restrict__ pn, int E) {
    __shared__ int lhs[PACKN];   // by src, 2 x u16 per word
    __shared__ int lhd[PACKN];   // by dst
    for (int i = threadIdx.x; i < PACKN; i += 512) { lhs[i] = 0; lhd[i] = 0; }
    __syncthreads();
    const int b = blockIdx.x;
    const int chunk = (E + HB - 1) / HB;
    const int e0 = b * chunk;
    const int e1 = (e0 + chunk < E) ? (e0 + chunk) : E;
    for (int e = e0 + threadIdx.x; e < e1; e += 512) {
        int s = ei[e], d = ei[E + e];
        atomicAdd(&lhs[s >> 1], 1 << ((s & 1) << 4));
        atomicAdd(&lhd[d >> 1], 1 << ((d & 1) << 4));
        pp[e] = make_int2(s, d);
        pn[e] = make_int2(nei[e], nei[E + e]);
    }
    __syncthreads();
    int* ds = degp + (size_t)b * PACKN;
    int* cs = cntp + (size_t)b * PACKN;
    for (int i = threadIdx.x; i < PACKN; i += 512) { ds[i] = lhs[i]; cs[i] = lhd[i]; }
}

// Merge: dinv[v]; off[b][v] (ushort) = prefix of cnt over blocks; rowptr[v+1].
// Thread 0 also zeroes the loss accumulator (replaces a memset dispatch).
__global__ void merge_kernel(const int* __restrict__ degp, const int* __restrict__ cntp,
                             ushort_t* __restrict__ off, int Nal,
                             float* __restrict__ dinv, int* __restrict__ rowptr,
                             float* __restrict__ acc, int n) {
    int v = blockIdx.x * blockDim.x + threadIdx.x;
    if (v == 0) {
        rowptr[0] = 0;
        acc[0] = 0.0f; acc[1] = 0.0f; acc[2] = 0.0f; acc[3] = 0.0f;
    }
    if (v >= n) return;
    const int vh = v >> 1, sh = (v & 1) << 4;
    int d = 0;
    for (int b = 0; b < HB; ++b)
        d += (degp[(size_t)b * PACKN + vh] >> sh) & 0xffff;
    dinv[v] = (d > 0) ? (1.0f / sqrtf((float)d)) : 0.0f;
    int run = 0;
    for (int b = 0; b < HB; ++b) {
        off[(size_t)b * Nal + v] = (ushort_t)run;
        run += (cntp[(size_t)b * PACKN + vh] >> sh) & 0xffff;
    }
    rowptr[v + 1] = run;
}

// single-block inclusive scan of rowptr[1..n]
__global__ void scan_kernel(int* __restrict__ rowptr, int n) {
    __shared__ int wsum[16];
    __shared__ int carry_s;
    if (threadIdx.x == 0) carry_s = 0;
    __syncthreads();
    int nchunk = (n + 1023) / 1024;
    int wid = threadIdx.x >> 6, lane = threadIdx.x & 63;
    for (int c = 0; c < nchunk; ++c) {
        int i = c * 1024 + threadIdx.x;
        int v = (i < n) ? rowptr[i + 1] : 0;
        int s = v;
        for (int off = 1; off < 64; off <<= 1) {
            int t = __shfl_up(s, off, 64);
            if (lane >= off) s += t;
        }
        if (lane == 63) wsum[wid] = s;
        __syncthreads();
        if (wid == 0 && lane < 16) {
            int wsv = wsum[lane];
            for (int off = 1; off < 16; off <<= 1) {
                int t = __shfl_up(wsv, off, 64);
                if (lane >= off) wsv += t;
            }
            wsum[lane] = wsv;
        }
        __syncthreads();
        int base = carry_s + (wid > 0 ? wsum[wid - 1] : 0);
        int inc = base + s;
        if (i < n) rowptr[i + 1] = inc;
        __syncthreads();
        if (threadIdx.x == 1023) carry_s = inc;
        __syncthreads();
    }
}

// Pass 2: fill CSR — rank via packed LDS returning atomic, slot computed.
__global__ __launch_bounds__(512) void fill_lds_kernel(
    const int* __restrict__ ei, const float* __restrict__ dinv,
    const int* __restrict__ rowptr, const ushort_t* __restrict__ off, int Nal,
    int* __restrict__ colidx, float* __restrict__ wnorm, int E) {
    __shared__ int lh[PACKN];
    for (int i = threadIdx.x; i < PACKN; i += 512) lh[i] = 0;
    __syncthreads();
    const int b = blockIdx.x;
    const int chunk = (E + HB - 1) / HB;
    const int e0 = b * chunk;
    const int e1 = (e0 + chunk < E) ? (e0 + chunk) : E;
    const ushort_t* boff = off + (size_t)b * Nal;
    for (int e = e0 + threadIdx.x; e < e1; e += 512) {
        int s = ei[e], d = ei[E + e];
        int sh = (d & 1) << 4;
        int old = atomicAdd(&lh[d >> 1], 1 << sh);
        int rank = (old >> sh) & 0xffff;
        int slot = rowptr[d] + (int)boff[d] + rank;
        colidx[slot] = s;
        wnorm[slot] = -dinv[s] * dinv[d];
    }
}

// XT[node] = [ x[node] (64) | segsum64(x)[node] (64) ] — one wave per node,
// 4 edges in flight + depth-1 row prefetch.
__global__ void xt_kernel(const float* __restrict__ x, const int* __restrict__ rowptr,
                          const int* __restrict__ colidx, const float* __restrict__ wnorm,
                          float* __restrict__ XT, int n) {
    int node = (blockIdx.x * blockDim.x + threadIdx.x) >> 6;
    if (node >= n) return;
    int lane = threadIdx.x & 63;
    int grp = lane >> 4;
    int l = lane & 15;
    int j0 = rowptr[node], j1 = rowptr[node + 1];
    float4 a = {0, 0, 0, 0};
    int j = j0 + grp;
    if (j < j1) {
        float w = wnorm[j];
        int c = colidx[j];
        float4 r = ((const float4*)(x + (size_t)c * 64))[l];
        for (;;) {
            int jn = j + 4;
            bool more = jn < j1;
            float wn = 0.0f;
            float4 rn = r;
            if (more) {
                int cn = colidx[jn];
                wn = wnorm[jn];
                rn = ((const float4*)(x + (size_t)cn * 64))[l];
            }
            a.x += w * r.x; a.y += w * r.y; a.z += w * r.z; a.w += w * r.w;
            if (!more) break;
            j = jn; w = wn; r = rn;
        }
    }
#pragma unroll
    for (int off = 16; off <= 32; off <<= 1) {
        a.x += __shfl_xor(a.x, off, 64);
        a.y += __shfl_xor(a.y, off, 64);
        a.z += __shfl_xor(a.z, off, 64);
        a.w += __shfl_xor(a.w, off, 64);
    }
    if (grp == 0) {
        float4 xv = ((const float4*)(x + (size_t)node * 64))[l];
        *(float4*)&XT[(size_t)node * 128 + l * 4] = xv;
        *(float4*)&XT[(size_t)node * 128 + 64 + l * 4] = a;
    }
}

// C = relu?( A @ Bcat + biascat ), bf16 MFMA 64x64x32.
// cols < split -> C[row*ldc + col]; cols >= split -> Cbf (bf16, rows of 128)
// if Cbf != nullptr, else C[row*ldc + col].
__global__ __launch_bounds__(256) void gemm_mfma(
    const float* __restrict__ A, int lda,
    const float* __restrict__ B0, const float* __restrict__ B1,
    const float* __restrict__ bias0, const float* __restrict__ bias1,
    float* __restrict__ C, int ldc, ushort_t* __restrict__ Cbf,
    int Nrows, int K, int Ncols, int split, int relu) {
    __shared__ short As[GBM * LDK];   // [m][k] bf16
    __shared__ short Bs[GBN * LDK];   // [n][k] bf16 (B transposed)
    const int bm = blockIdx.y * GBM, bn = blockIdx.x * GBN;
    const int tid = threadIdx.x;
    const int w = tid >> 6, l = tid & 63;
    const int wm = (w >> 1) * 32, wn = (w & 1) * 32;
    const int lr = l & 15;
    const int kg = l >> 4;
    const int arow = tid >> 2, aseg = tid & 3;
    const int bcol = tid & 63, bk2 = (tid >> 6) * 2;
    const int ldb0 = split, ldb1 = Ncols - split;

    const int arowg = bm + arow;
    const int bcolg = bn + bcol;
    const float* Bsrc = (bcolg < split) ? (B0 + bcolg)
                       : ((bcolg < Ncols) ? (B1 + (bcolg - split)) : nullptr);
    const int ldb = (bcolg < split) ? ldb0 : ldb1;

    f32x4 acc00 = {0,0,0,0}, acc01 = {0,0,0,0}, acc10 = {0,0,0,0}, acc11 = {0,0,0,0};

    for (int k0 = 0; k0 < K; k0 += GBK) {
        {
            int kk = k0 + aseg * 8;
            bf16x8 v;
            if (arowg < Nrows && kk + 7 < K) {
                float4 f0 = *(const float4*)&A[(size_t)arowg * lda + kk];
                float4 f1 = *(const float4*)&A[(size_t)arowg * lda + kk + 4];
                v[0] = f2bf(f0.x); v[1] = f2bf(f0.y); v[2] = f2bf(f0.z); v[3] = f2bf(f0.w);
                v[4] = f2bf(f1.x); v[5] = f2bf(f1.y); v[6] = f2bf(f1.z); v[7] = f2bf(f1.w);
            } else {
#pragma unroll
                for (int i = 0; i < 8; ++i)
                    v[i] = (arowg < Nrows && kk + i < K)
                         ? f2bf(A[(size_t)arowg * lda + kk + i]) : (short)0;
            }
            *(bf16x8*)&As[arow * LDK + aseg * 8] = v;
        }
#pragma unroll
        for (int q = 0; q < 4; ++q) {
            int k = q * 8 + bk2;
            unsigned pw = 0u;
            if (Bsrc) {
                float f0 = (k0 + k < K) ? Bsrc[(size_t)(k0 + k) * ldb] : 0.0f;
                float f1 = (k0 + k + 1 < K) ? Bsrc[(size_t)(k0 + k + 1) * ldb] : 0.0f;
                pw = (unsigned)(unsigned short)f2bf(f0)
                   | ((unsigned)(unsigned short)f2bf(f1) << 16);
            }
            *(unsigned*)&Bs[bcol * LDK + k] = pw;
        }
        __syncthreads();
        bf16x8 a0 = *(const bf16x8*)&As[(wm + lr) * LDK + kg * 8];
        bf16x8 a1 = *(const bf16x8*)&As[(wm + 16 + lr) * LDK + kg * 8];
        bf16x8 b0 = *(const bf16x8*)&Bs[(wn + lr) * LDK + kg * 8];
        bf16x8 b1 = *(const bf16x8*)&Bs[(wn + 16 + lr) * LDK + kg * 8];
        acc00 = __builtin_amdgcn_mfma_f32_16x16x32_bf16(a0, b0, acc00, 0, 0, 0);
        acc01 = __builtin_amdgcn_mfma_f32_16x16x32_bf16(a0, b1, acc01, 0, 0, 0);
        acc10 = __builtin_amdgcn_mfma_f32_16x16x32_bf16(a1, b0, acc10, 0, 0, 0);
        acc11 = __builtin_amdgcn_mfma_f32_16x16x32_bf16(a1, b1, acc11, 0, 0, 0);
        __syncthreads();
    }
#pragma unroll
    for (int i = 0; i < 2; ++i) {
        int rbase = bm + wm + i * 16 + kg * 4;
#pragma unroll
        for (int j = 0; j < 2; ++j) {
            int col = bn + wn + j * 16 + lr;
            if (col >= Ncols) continue;
            float bv = (col < split) ? (bias0 ? bias0[col] : 0.0f)
                                     : (bias1 ? bias1[col - split] : 0.0f);
            f32x4 a = (i == 0) ? (j == 0 ? acc00 : acc01) : (j == 0 ? acc10 : acc11);
#pragma unroll
            for (int r = 0; r < 4; ++r) {
                int row = rbase + r;
                if (row >= Nrows) continue;
                float o = a[r] + bv;
                if (relu) o = fmaxf(o, 0.0f);
                if (col < split || !Cbf)
                    C[(size_t)row * ldc + col] = o;
                else
                    Cbf[(size_t)row * 128 + (col - split)] = (ushort_t)f2bf(o);
            }
        }
    }
}

// t = segsum(hWb); x1 = relu(G2a + t + b2) — fused epilogue, depth-1 row prefetch.
__global__ void segsum_combine1_kernel(const ushort_t* __restrict__ hb,
                                       const int* __restrict__ rowptr, const int* __restrict__ colidx,
                                       const float* __restrict__ wnorm,
                                       const float* __restrict__ G2a, const float* __restrict__ b2,
                                       float* __restrict__ x1, int n) {
    int node = (blockIdx.x * blockDim.x + threadIdx.x) >> 6;
    if (node >= n) return;
    int lane = threadIdx.x & 63;
    int grp = lane >> 4;
    int l = lane & 15;
    int j0 = rowptr[node], j1 = rowptr[node + 1];
    float acc[8] = {};
    int j = j0 + grp;
    if (j < j1) {
        float w = wnorm[j];
        int c = colidx[j];
        uint4 r = ((const uint4*)(hb + (size_t)c * 128))[l];
        for (;;) {
            int jn = j + 4;
            bool more = jn < j1;
            float wn = 0.0f;
            uint4 rn = r;
            if (more) {
                int cn = colidx[jn];
                wn = wnorm[jn];
                rn = ((const uint4*)(hb + (size_t)cn * 128))[l];
            }
            acc[0] += w * bflo(r.x); acc[1] += w * bfhi(r.x);
            acc[2] += w * bflo(r.y); acc[3] += w * bfhi(r.y);
            acc[4] += w * bflo(r.z); acc[5] += w * bfhi(r.z);
            acc[6] += w * bflo(r.w); acc[7] += w * bfhi(r.w);
            if (!more) break;
            j = jn; w = wn; r = rn;
        }
    }
#pragma unroll
    for (int k = 0; k < 8; ++k) {
        acc[k] += __shfl_xor(acc[k], 16, 64);
        acc[k] += __shfl_xor(acc[k], 32, 64);
    }
    if (grp == 0) {
        int f = l * 8;
        if (f < 100) {
            float4 g0 = *(const float4*)&G2a[(size_t)node * 100 + f];
            float4 bv0 = *(const float4*)&b2[f];
            float4 o0;
            o0.x = fmaxf(g0.x + acc[0] + bv0.x, 0.0f);
            o0.y = fmaxf(g0.y + acc[1] + bv0.y, 0.0f);
            o0.z = fmaxf(g0.z + acc[2] + bv0.z, 0.0f);
            o0.w = fmaxf(g0.w + acc[3] + bv0.w, 0.0f);
            *(float4*)&x1[(size_t)node * 100 + f] = o0;
            if (f + 8 <= 100) {
                float4 g1 = *(const float4*)&G2a[(size_t)node * 100 + f + 4];
                float4 bv1 = *(const float4*)&b2[f + 4];
                float4 o1;
                o1.x = fmaxf(g1.x + acc[4] + bv1.x, 0.0f);
                o1.y = fmaxf(g1.y + acc[5] + bv1.y, 0.0f);
                o1.z = fmaxf(g1.z + acc[6] + bv1.z, 0.0f);
                o1.w = fmaxf(g1.w + acc[7] + bv1.w, 0.0f);
                *(float4*)&x1[(size_t)node * 100 + f + 4] = o1;
            }
        }
    }
}

// xo = x1 + relu(S[:,0:100]); zf = fp8(x1 + relu(S[:,100:200]));
// sv[i] = xo[i,:] @ w3b (fused rowdot via 32-lane shfl reduce).
__global__ void combine2_kernel(const float* __restrict__ S, const float* __restrict__ x1,
                                const float* __restrict__ w3b,
                                float* __restrict__ xo, unsigned* __restrict__ zf,
                                float* __restrict__ sv, int n) {
    int idx = blockIdx.x * blockDim.x + threadIdx.x;
    if (idx >= n * 32) return;
    int i = idx >> 5, q = idx & 31;
    unsigned w = 0u;
    float part = 0.0f;
    if (q < 25) {
        float4 s1 = *(const float4*)&S[(size_t)i * 200 + q * 4];
        float4 s2 = *(const float4*)&S[(size_t)i * 200 + 100 + q * 4];
        float4 xv = *(const float4*)&x1[(size_t)i * 100 + q * 4];
        float4 a, b;
        a.x = xv.x + fmaxf(s1.x, 0.0f); a.y = xv.y + fmaxf(s1.y, 0.0f);
        a.z = xv.z + fmaxf(s1.z, 0.0f); a.w = xv.w + fmaxf(s1.w, 0.0f);
        b.x = xv.x + fmaxf(s2.x, 0.0f); b.y = xv.y + fmaxf(s2.y, 0.0f);
        b.z = xv.z + fmaxf(s2.z, 0.0f); b.w = xv.w + fmaxf(s2.w, 0.0f);
        *(float4*)&xo[(size_t)i * 100 + q * 4] = a;
        w = (unsigned)__builtin_amdgcn_cvt_pk_fp8_f32(b.x, b.y, 0, false);
        w = (unsigned)__builtin_amdgcn_cvt_pk_fp8_f32(b.z, b.w, (int)w, true);
        float4 wv = *(const float4*)&w3b[q * 4];
        part = a.x * wv.x + a.y * wv.y + a.z * wv.z + a.w * wv.w;
    }
    zf[(size_t)i * 32 + q] = w;
#pragma unroll
    for (int off = 16; off > 0; off >>= 1)
        part += __shfl_xor(part, off, 32);
    if (q == 0) sv[i] = part;
}

// fused pos/neg loss on fp8 z rows: 8 lanes/edge, uint4/lane = full 128B row.
// TWO independent edge streams per group (A: g+2t*ng, B: g+ng+2t*ng), each
// with depth-2 index + depth-1 row prefetch -> 8 row loads in flight.
__global__ __launch_bounds__(256) void edge_loss_fp8_kernel(
    const unsigned* __restrict__ zf, const int2* __restrict__ pp,
    const int2* __restrict__ pn, int E, float* __restrict__ accv) {
    const int y = blockIdx.y;
    const int2* __restrict__ pairs = y ? pn : pp;
    const int l = threadIdx.x & 7;
    const int g = (blockIdx.x * blockDim.x + threadIdx.x) >> 3;
    const int ng = (gridDim.x * blockDim.x) >> 3;
    const int stride2 = 2 * ng;
    float s = 0.0f;
    const int gA = g, gB = g + ng;
    int niterA = (gA < E) ? ((E - 1 - gA) / stride2 + 1) : 0;
    int niterB = (gB < E) ? ((E - 1 - gB) / stride2 + 1) : 0;
    if (niterA > 0) {
        int eB0 = (gB < E) ? gB : (E - 1);
        int eA1 = (gA + stride2 < E) ? (gA + stride2) : (E - 1);
        int eB1 = (gB + stride2 < E) ? (gB + stride2) : (E - 1);
        int2 pA0 = pairs[gA], pB0 = pairs[eB0];
        int2 pA1 = pairs[eA1], pB1 = pairs[eB1];
        uint4 raA = *(const uint4*)&zf[(size_t)pA0.x * 32 + l * 4];
        uint4 rbA = *(const uint4*)&zf[(size_t)pA0.y * 32 + l * 4];
        uint4 raB = *(const uint4*)&zf[(size_t)pB0.x * 32 + l * 4];
        uint4 rbB = *(const uint4*)&zf[(size_t)pB0.y * 32 + l * 4];
        for (int t = 0; t < niterA; ++t) {
            int eA2 = gA + (t + 2) * stride2; eA2 = (eA2 < E) ? eA2 : (E - 1);
            int eB2 = gB + (t + 2) * stride2; eB2 = (eB2 < E) ? eB2 : (E - 1);
            int2 pA2 = pairs[eA2], pB2 = pairs[eB2];
            uint4 raA1 = *(const uint4*)&zf[(size_t)pA1.x * 32 + l * 4];
            uint4 rbA1 = *(const uint4*)&zf[(size_t)pA1.y * 32 + l * 4];
            uint4 raB1 = *(const uint4*)&zf[(size_t)pB1.x * 32 + l * 4];
            uint4 rbB1 = *(const uint4*)&zf[(size_t)pB1.y * 32 + l * 4];
            float dA = dot16fp8(raA, rbA);
            float dB = dot16fp8(raB, rbB);
            dA += __shfl_xor(dA, 1, 8); dB += __shfl_xor(dB, 1, 8);
            dA += __shfl_xor(dA, 2, 8); dB += __shfl_xor(dB, 2, 8);
            dA += __shfl_xor(dA, 4, 8); dB += __shfl_xor(dB, 4, 8);
            if (l == 0) {
                float sgA = 1.0f / (1.0f + expf(-dA));
                s += y ? logf(1.0f - sgA + 1e-15f) : logf(sgA + 1e-15f);
                if (t < niterB) {
                    float sgB = 1.0f / (1.0f + expf(-dB));
                    s += y ? logf(1.0f - sgB + 1e-15f) : logf(sgB + 1e-15f);
                }
            }
            pA1 = pA2; pB1 = pB2;
            raA = raA1; rbA = rbA1; raB = raB1; rbB = rbB1;
        }
    }
    __shared__ float red[256];
    red[threadIdx.x] = s;
    __syncthreads();
    for (int st = 128; st > 0; st >>= 1) {
        if (threadIdx.x < st) red[threadIdx.x] += red[threadIdx.x + st];
        __syncthreads();
    }
    if (threadIdx.x == 0) atomicAdd(&accv[y], red[0]);
}

// out[i] = xo[i,:]@W3[0] + b3 + sum_j wnorm[j]*sv[colidx[j]]; thread 0 also
// writes r_loss/c1/c2 tail (acc is final: edge_loss precedes on stream).
__global__ void out_finalize_kernel(const float* __restrict__ xo, const float* __restrict__ W3,
                                    const float* __restrict__ b3, const int* __restrict__ rowptr,
                                    const int* __restrict__ colidx, const float* __restrict__ wnorm,
                                    const float* __restrict__ sv, const float* __restrict__ accv,
                                    const float* __restrict__ c1, const float* __restrict__ c2,
                                    float* __restrict__ out, int n, int E) {
    int i = blockIdx.x * blockDim.x + threadIdx.x;
    if (i == 0) {
        out[n]     = -(accv[0] + accv[1]) / (float)E;
        out[n + 1] = c1[0];
        out[n + 2] = c2[0];
    }
    if (i >= n) return;
    const float4* a = (const float4*)(xo + (size_t)i * 100);
    const float4* wv = (const float4*)W3;
    float acc = b3[0];
#pragma unroll
    for (int q = 0; q < 25; ++q) {
        float4 va = a[q], vw = wv[q];
        acc += va.x * vw.x + va.y * vw.y + va.z * vw.z + va.w * vw.w;
    }
    int j1 = rowptr[i + 1];
    for (int j = rowptr[i]; j < j1; ++j)
        acc += wnorm[j] * sv[colidx[j]];
    out[i] = acc;
}

extern "C" void kernel_launch(void* const* d_in, const int* in_sizes, int n_in,
                              void* d_out, int out_size, void* d_ws, size_t ws_size,
                              hipStream_t stream) {
    (void)n_in; (void)out_size; (void)ws_size;
    const float* x   = (const float*)d_in[0];
    const int*   ei  = (const int*)d_in[1];
    const int*   nei = (const int*)d_in[2];
    const float* W1  = (const float*)d_in[3];
    const float* b1  = (const float*)d_in[4];
    const float* W2  = (const float*)d_in[5];
    const float* b2  = (const float*)d_in[6];
    const float* W3  = (const float*)d_in[7];
    const float* b3  = (const float*)d_in[8];
    const float* lw1 = (const float*)d_in[9];
    const float* lb1 = (const float*)d_in[10];
    const float* lw2 = (const float*)d_in[11];
    const float* lb2 = (const float*)d_in[12];
    const float* c1  = (const float*)d_in[13];
    const float* c2  = (const float*)d_in[14];

    const int Nn = in_sizes[0] / 64;   // 13627
    const int E  = in_sizes[1] / 2;    // 504378

    const size_t Nal = ((size_t)Nn + 5) & ~(size_t)3;   // >= N+1, mult of 4
    const size_t Eal = ((size_t)E + 3) & ~(size_t)3;

    float* ws       = (float*)d_ws;
    float* acc      = ws;                           // 4 floats
    float* dinv     = acc + 4;                      // Nal
    int*   rowptr   = (int*)(dinv + Nal);           // Nal (N+1 used)
    int*   colidx   = rowptr + Nal;                 // Eal
    float* wnorm    = (float*)(colidx + Eal);       // Eal
    int2*  pp       = (int2*)(wnorm + Eal);         // Eal int2
    int2*  pn       = pp + Eal;                     // Eal int2
    int*   degp     = (int*)(pn + Eal);             // HB*PACKN ints
    int*   cntp     = degp + (size_t)HB * PACKN;    // HB*PACKN ints
    ushort_t* offus = (ushort_t*)(cntp + (size_t)HB * PACKN);  // HB*Nal ushorts
    float* XT       = (float*)(offus + (size_t)HB * Nal);      // N*128
    float* h        = XT + (size_t)Nn * 128;        // N*300 (alias S: N*200)
    float* G2a      = h  + (size_t)Nn * 300;        // N*100
    float* x1       = G2a + (size_t)Nn * 100;       // N*100
    float* xo       = x1 + (size_t)Nn * 100;        // N*100
    size_t zoff     = (size_t)(xo + (size_t)Nn * 100 - ws);
    zoff = (zoff + 31) & ~(size_t)31;               // 128B align
    unsigned* zf    = (unsigned*)(ws + zoff);       // N*32 words (fp8 rows, 128B)
    size_t hoff     = zoff + (size_t)Nn * 32 + 63;
    hoff &= ~(size_t)63;                            // 256B align
    ushort_t* hWb   = (ushort_t*)(ws + hoff);       // N*128 bf16 (256B rows)
    float* sv       = ws + hoff + (size_t)Nn * 64;  // Nal
    float* S        = h;                            // alias (h dead after conv2 gemm)

    const int MB = (Nn + GBM - 1) / GBM;

    // --- CSR build: packed LDS histograms, zero global atomics, no memset ---
    hist_both_pairs_kernel<<<HB, 512, 0, stream>>>(ei, nei, degp, cntp, pp, pn, E);
    merge_kernel<<<(Nn + 255) / 256, 256, 0, stream>>>(degp, cntp, offus, (int)Nal,
                                                       dinv, rowptr, acc, Nn);
    scan_kernel<<<1, 1024, 0, stream>>>(rowptr, Nn);
    fill_lds_kernel<<<HB, 512, 0, stream>>>(ei, dinv, rowptr, offus, (int)Nal,
                                            colidx, wnorm, E);

    // --- conv1: XT = [x | segsum64(x)]; h = relu(XT @ W1cat + b1) ---
    xt_kernel<<<(Nn + 3) / 4, 256, 0, stream>>>(x, rowptr, colidx, wnorm, XT, Nn);
    gemm_mfma<<<dim3(5, MB), 256, 0, stream>>>(
        XT, 128, W1, nullptr, b1, nullptr, h, 300, nullptr, Nn, 128, 300, 300, 1);

    // --- conv2 fused: [G2a | hWb(bf16)] = h @ [W2[0] | W2[1]] (pack fused) ---
    gemm_mfma<<<dim3(4, MB), 256, 0, stream>>>(
        h, 300, W2, W2 + 300 * 100, nullptr, nullptr, G2a, 100, hWb, Nn, 300, 200, 100, 0);
    // x1 = relu(G2a + segsum(hWb) + b2) fused
    segsum_combine1_kernel<<<(Nn + 3) / 4, 256, 0, stream>>>(hWb, rowptr, colidx, wnorm,
                                                             G2a, b2, x1, Nn);

    // --- skips fused: S = x @ [lw1|lw2] + [lb1|lb2];
    //     combine2: xo = x1+relu(S0), zf = fp8(x1+relu(S1)), sv = xo@W3[1] ---
    gemm_mfma<<<dim3(4, MB), 256, 0, stream>>>(
        x, 64, lw1, lw2, lb1, lb2, S, 200, nullptr, Nn, 64, 200, 100, 0);
    combine2_kernel<<<(Nn * 32 + 255) / 256, 256, 0, stream>>>(S, x1, W3 + 100,
                                                               xo, zf, sv, Nn);

    // --- edge reconstruction losses (pos: y=0, neg: y=1), fp8 z, 2 streams ---
    edge_loss_fp8_kernel<<<dim3(1024, 2), 256, 0, stream>>>(zf, pp, pn, E, acc);

    // --- conv3 (width 1) + finalize: out = xo@W3[0] + segsum(sv) + b3; tail ---
    out_finalize_kernel<<<(Nn + 255) / 256, 256, 0, stream>>>(
        xo, W3, b3, rowptr, colidx, wnorm, sv, acc, c1, c2, (float*)d_out, Nn, E);
}

// Round 15
// 215.097 us; speedup vs baseline: 1.2762x; 1.1172x over previous
//
#include <hip/hip_runtime.h>
#include <math.h>

// ---------------------------------------------------------------------------
// Net_1503238553644: 2-layer ChebConv(K=2) GNN + linear skips + edge recon loss
// N=13627, E=504378, F=64, H1=300, H2=100, LIN=100
// R15: bf16 dataflow (xb/XTb/h-bf16, gemm bf16-A path), pp/pn dropped
//      (edge_loss reads ei/nei direct), merge 4-threads/node. 12 launches.
// ---------------------------------------------------------------------------

typedef unsigned short ushort_t;
typedef float v2f __attribute__((ext_vector_type(2)));
typedef short bf16x8 __attribute__((ext_vector_type(8)));
typedef float f32x4 __attribute__((ext_vector_type(4)));

#define GBM 64
#define GBN 64
#define GBK 32
#define LDK 72    // bf16 per LDS row: 144B, 16B-aligned, 2-way bank alias (free)
#define HB  256   // histogram blocks (all CUs)
#define PACKN 6816  // ceil(13632/2) packed histogram words

__device__ inline short f2bf(float f) {              // RNE float->bf16
    unsigned u = __float_as_uint(f);
    u += 0x7fff + ((u >> 16) & 1);
    return (short)(u >> 16);
}
__device__ inline float bflo(unsigned w) { return __uint_as_float(w << 16); }
__device__ inline float bfhi(unsigned w) { return __uint_as_float(w & 0xffff0000u); }

// fp8x16 dot (two 128-bit regs = 16 e4m3 each), HW cvt_pk decode
__device__ inline float dot16fp8(uint4 ra, uint4 rb) {
    float dot = 0.0f;
    v2f fa, fb;
    fa = __builtin_amdgcn_cvt_pk_f32_fp8(ra.x, false);
    fb = __builtin_amdgcn_cvt_pk_f32_fp8(rb.x, false);
    dot += fa.x * fb.x + fa.y * fb.y;
    fa = __builtin_amdgcn_cvt_pk_f32_fp8(ra.x, true);
    fb = __builtin_amdgcn_cvt_pk_f32_fp8(rb.x, true);
    dot += fa.x * fb.x + fa.y * fb.y;
    fa = __builtin_amdgcn_cvt_pk_f32_fp8(ra.y, false);
    fb = __builtin_amdgcn_cvt_pk_f32_fp8(rb.y, false);
    dot += fa.x * fb.x + fa.y * fb.y;
    fa = __builtin_amdgcn_cvt_pk_f32_fp8(ra.y, true);
    fb = __builtin_amdgcn_cvt_pk_f32_fp8(rb.y, true);
    dot += fa.x * fb.x + fa.y * fb.y;
    fa = __builtin_amdgcn_cvt_pk_f32_fp8(ra.z, false);
    fb = __builtin_amdgcn_cvt_pk_f32_fp8(rb.z, false);
    dot += fa.x * fb.x + fa.y * fb.y;
    fa = __builtin_amdgcn_cvt_pk_f32_fp8(ra.z, true);
    fb = __builtin_amdgcn_cvt_pk_f32_fp8(rb.z, true);
    dot += fa.x * fb.x + fa.y * fb.y;
    fa = __builtin_amdgcn_cvt_pk_f32_fp8(ra.w, false);
    fb = __builtin_amdgcn_cvt_pk_f32_fp8(rb.w, false);
    dot += fa.x * fb.x + fa.y * fb.y;
    fa = __builtin_amdgcn_cvt_pk_f32_fp8(ra.w, true);
    fb = __builtin_amdgcn_cvt_pk_f32_fp8(rb.w, true);
    dot += fa.x * fb.x + fa.y * fb.y;
    return dot;
}

// Pass 1: packed dual LDS histograms (src + dst) in one edge pass; tail packs
// this block's slice of x into bf16 rows (xb).
__global__ __launch_bounds__(512) void hist_both_x_kernel(
    const int* __restrict__ ei, const float* __restrict__ x,
    int* __restrict__ degp, int* __restrict__ cntp,
    ushort_t* __restrict__ xb, int Nn, int E) {
    __shared__ int lhs[PACKN];   // by src, 2 x u16 per word
    __shared__ int lhd[PACKN];   // by dst
    for (int i = threadIdx.x; i < PACKN; i += 512) { lhs[i] = 0; lhd[i] = 0; }
    __syncthreads();
    const int b = blockIdx.x;
    const int chunk = (E + HB - 1) / HB;
    const int e0 = b * chunk;
    const int e1 = (e0 + chunk < E) ? (e0 + chunk) : E;
    for (int e = e0 + threadIdx.x; e < e1; e += 512) {
        int s = ei[e], d = ei[E + e];
        atomicAdd(&lhs[s >> 1], 1 << ((s & 1) << 4));
        atomicAdd(&lhd[d >> 1], 1 << ((d & 1) << 4));
    }
    __syncthreads();
    int* ds = degp + (size_t)b * PACKN;
    int* cs = cntp + (size_t)b * PACKN;
    for (int i = threadIdx.x; i < PACKN; i += 512) { ds[i] = lhs[i]; cs[i] = lhd[i]; }
    // pack this block's slice of x to bf16
    const int rpb = (Nn + HB - 1) / HB;
    const int r0 = b * rpb;
    const int r1 = (r0 + rpb < Nn) ? (r0 + rpb) : Nn;
    for (int i = r0 * 64 + (int)threadIdx.x; i < r1 * 64; i += 512)
        xb[i] = (ushort_t)f2bf(x[i]);
}

// Merge: 4 threads per node, each owning 64 block-slices. dinv[v]; off[b][v]
// (ushort) = prefix of cnt over blocks; rowptr[v+1]. tid 0 zeroes acc.
__global__ void merge_kernel(const int* __restrict__ degp, const int* __restrict__ cntp,
                             ushort_t* __restrict__ off, int Nal,
                             float* __restrict__ dinv, int* __restrict__ rowptr,
                             float* __restrict__ acc, int n) {
    int tid = blockIdx.x * blockDim.x + threadIdx.x;
    if (tid == 0) {
        rowptr[0] = 0;
        acc[0] = 0.0f; acc[1] = 0.0f; acc[2] = 0.0f; acc[3] = 0.0f;
    }
    int v = tid >> 2, qq = tid & 3;
    if (v >= n) return;
    const int vh = v >> 1, sh = (v & 1) << 4;
    const int b0 = qq * (HB / 4), b1 = b0 + HB / 4;
    int dsum = 0, csum = 0;
    for (int b = b0; b < b1; ++b) {
        dsum += (degp[(size_t)b * PACKN + vh] >> sh) & 0xffff;
        csum += (cntp[(size_t)b * PACKN + vh] >> sh) & 0xffff;
    }
    // total deg across the 4 lanes of this node
    int dtot = dsum;
    dtot += __shfl_xor(dtot, 1, 64);
    dtot += __shfl_xor(dtot, 2, 64);
    // inclusive prefix of csum across qq (4-lane group, aligned)
    int inc = csum;
    int t = __shfl_up(inc, 1, 64); if (qq >= 1) inc += t;
    t = __shfl_up(inc, 2, 64);     if (qq >= 2) inc += t;
    int ex = inc - csum;
    if (qq == 0) dinv[v] = (dtot > 0) ? (1.0f / sqrtf((float)dtot)) : 0.0f;
    if (qq == 3) rowptr[v + 1] = inc;
    int run = ex;
    for (int b = b0; b < b1; ++b) {
        off[(size_t)b * Nal + v] = (ushort_t)run;
        run += (cntp[(size_t)b * PACKN + vh] >> sh) & 0xffff;
    }
}

// single-block inclusive scan of rowptr[1..n]
__global__ void scan_kernel(int* __restrict__ rowptr, int n) {
    __shared__ int wsum[16];
    __shared__ int carry_s;
    if (threadIdx.x == 0) carry_s = 0;
    __syncthreads();
    int nchunk = (n + 1023) / 1024;
    int wid = threadIdx.x >> 6, lane = threadIdx.x & 63;
    for (int c = 0; c < nchunk; ++c) {
        int i = c * 1024 + threadIdx.x;
        int v = (i < n) ? rowptr[i + 1] : 0;
        int s = v;
        for (int off = 1; off < 64; off <<= 1) {
            int t = __shfl_up(s, off, 64);
            if (lane >= off) s += t;
        }
        if (lane == 63) wsum[wid] = s;
        __syncthreads();
        if (wid == 0 && lane < 16) {
            int wsv = wsum[lane];
            for (int off = 1; off < 16; off <<= 1) {
                int t = __shfl_up(wsv, off, 64);
                if (lane >= off) wsv += t;
            }
            wsum[lane] = wsv;
        }
        __syncthreads();
        int base = carry_s + (wid > 0 ? wsum[wid - 1] : 0);
        int inc = base + s;
        if (i < n) rowptr[i + 1] = inc;
        __syncthreads();
        if (threadIdx.x == 1023) carry_s = inc;
        __syncthreads();
    }
}

// Pass 2: fill CSR — rank via packed LDS returning atomic, slot computed.
__global__ __launch_bounds__(512) void fill_lds_kernel(
    const int* __restrict__ ei, const float* __restrict__ dinv,
    const int* __restrict__ rowptr, const ushort_t* __restrict__ off, int Nal,
    int* __restrict__ colidx, float* __restrict__ wnorm, int E) {
    __shared__ int lh[PACKN];
    for (int i = threadIdx.x; i < PACKN; i += 512) lh[i] = 0;
    __syncthreads();
    const int b = blockIdx.x;
    const int chunk = (E + HB - 1) / HB;
    const int e0 = b * chunk;
    const int e1 = (e0 + chunk < E) ? (e0 + chunk) : E;
    const ushort_t* boff = off + (size_t)b * Nal;
    for (int e = e0 + threadIdx.x; e < e1; e += 512) {
        int s = ei[e], d = ei[E + e];
        int sh = (d & 1) << 4;
        int old = atomicAdd(&lh[d >> 1], 1 << sh);
        int rank = (old >> sh) & 0xffff;
        int slot = rowptr[d] + (int)boff[d] + rank;
        colidx[slot] = s;
        wnorm[slot] = -dinv[s] * dinv[d];
    }
}

// XTb[node] = [ xb[node] (64 bf16) | bf16(segsum64(xb))[node] ] — one wave per
// node, 4 edges in flight (16-lane groups, uint2 = 4 bf16/lane), depth-1 prefetch.
__global__ void xt_kernel(const ushort_t* __restrict__ xb, const int* __restrict__ rowptr,
                          const int* __restrict__ colidx, const float* __restrict__ wnorm,
                          ushort_t* __restrict__ XTb, int n) {
    int node = (blockIdx.x * blockDim.x + threadIdx.x) >> 6;
    if (node >= n) return;
    int lane = threadIdx.x & 63;
    int grp = lane >> 4;
    int l = lane & 15;
    int j0 = rowptr[node], j1 = rowptr[node + 1];
    float a0 = 0, a1 = 0, a2 = 0, a3 = 0;
    int j = j0 + grp;
    if (j < j1) {
        float w = wnorm[j];
        int c = colidx[j];
        uint2 r = ((const uint2*)(xb + (size_t)c * 64))[l];
        for (;;) {
            int jn = j + 4;
            bool more = jn < j1;
            float wn = 0.0f;
            uint2 rn = r;
            if (more) {
                int cn = colidx[jn];
                wn = wnorm[jn];
                rn = ((const uint2*)(xb + (size_t)cn * 64))[l];
            }
            a0 += w * bflo(r.x); a1 += w * bfhi(r.x);
            a2 += w * bflo(r.y); a3 += w * bfhi(r.y);
            if (!more) break;
            j = jn; w = wn; r = rn;
        }
    }
    a0 += __shfl_xor(a0, 16, 64); a0 += __shfl_xor(a0, 32, 64);
    a1 += __shfl_xor(a1, 16, 64); a1 += __shfl_xor(a1, 32, 64);
    a2 += __shfl_xor(a2, 16, 64); a2 += __shfl_xor(a2, 32, 64);
    a3 += __shfl_xor(a3, 16, 64); a3 += __shfl_xor(a3, 32, 64);
    if (grp == 0) {
        uint2 xv = ((const uint2*)(xb + (size_t)node * 64))[l];
        *(uint2*)&XTb[(size_t)node * 128 + l * 4] = xv;
        uint2 p;
        p.x = (unsigned)(unsigned short)f2bf(a0) | ((unsigned)(unsigned short)f2bf(a1) << 16);
        p.y = (unsigned)(unsigned short)f2bf(a2) | ((unsigned)(unsigned short)f2bf(a3) << 16);
        *(uint2*)&XTb[(size_t)node * 128 + 64 + l * 4] = p;
    }
}

// C = relu?( A @ Bcat + biascat ), bf16 MFMA 64x64x32.
// A source: Abf (bf16, stride lda) if non-null, else A (f32, stride lda).
// Output: cbf_mode 0 -> all f32 C (ldc); 1 -> col<split f32 C, col>=split bf16
// Cbf (stride 128); 2 -> all bf16 Cbf (stride ldcbf).
__global__ __launch_bounds__(256) void gemm_mfma(
    const float* __restrict__ A, const ushort_t* __restrict__ Abf, int lda,
    const float* __restrict__ B0, const float* __restrict__ B1,
    const float* __restrict__ bias0, const float* __restrict__ bias1,
    float* __restrict__ C, int ldc, ushort_t* __restrict__ Cbf, int ldcbf,
    int cbf_mode, int Nrows, int K, int Ncols, int split, int relu) {
    __shared__ short As[GBM * LDK];   // [m][k] bf16
    __shared__ short Bs[GBN * LDK];   // [n][k] bf16 (B transposed)
    const int bm = blockIdx.y * GBM, bn = blockIdx.x * GBN;
    const int tid = threadIdx.x;
    const int w = tid >> 6, l = tid & 63;
    const int wm = (w >> 1) * 32, wn = (w & 1) * 32;
    const int lr = l & 15;
    const int kg = l >> 4;
    const int arow = tid >> 2, aseg = tid & 3;
    const int bcol = tid & 63, bk2 = (tid >> 6) * 2;
    const int ldb0 = split, ldb1 = Ncols - split;

    const int arowg = bm + arow;
    const int bcolg = bn + bcol;
    const float* Bsrc = (bcolg < split) ? (B0 + bcolg)
                       : ((bcolg < Ncols) ? (B1 + (bcolg - split)) : nullptr);
    const int ldb = (bcolg < split) ? ldb0 : ldb1;

    f32x4 acc00 = {0,0,0,0}, acc01 = {0,0,0,0}, acc10 = {0,0,0,0}, acc11 = {0,0,0,0};

    for (int k0 = 0; k0 < K; k0 += GBK) {
        {
            int kk = k0 + aseg * 8;
            bf16x8 v;
            if (Abf) {
                if (arowg < Nrows && kk + 7 < K) {
                    v = *(const bf16x8*)&Abf[(size_t)arowg * lda + kk];
                } else {
#pragma unroll
                    for (int i = 0; i < 8; ++i)
                        v[i] = (arowg < Nrows && kk + i < K)
                             ? (short)Abf[(size_t)arowg * lda + kk + i] : (short)0;
                }
            } else if (arowg < Nrows && kk + 7 < K) {
                float4 f0 = *(const float4*)&A[(size_t)arowg * lda + kk];
                float4 f1 = *(const float4*)&A[(size_t)arowg * lda + kk + 4];
                v[0] = f2bf(f0.x); v[1] = f2bf(f0.y); v[2] = f2bf(f0.z); v[3] = f2bf(f0.w);
                v[4] = f2bf(f1.x); v[5] = f2bf(f1.y); v[6] = f2bf(f1.z); v[7] = f2bf(f1.w);
            } else {
#pragma unroll
                for (int i = 0; i < 8; ++i)
                    v[i] = (arowg < Nrows && kk + i < K)
                         ? f2bf(A[(size_t)arowg * lda + kk + i]) : (short)0;
            }
            *(bf16x8*)&As[arow * LDK + aseg * 8] = v;
        }
#pragma unroll
        for (int q = 0; q < 4; ++q) {
            int k = q * 8 + bk2;
            unsigned pw = 0u;
            if (Bsrc) {
                float f0 = (k0 + k < K) ? Bsrc[(size_t)(k0 + k) * ldb] : 0.0f;
                float f1 = (k0 + k + 1 < K) ? Bsrc[(size_t)(k0 + k + 1) * ldb] : 0.0f;
                pw = (unsigned)(unsigned short)f2bf(f0)
                   | ((unsigned)(unsigned short)f2bf(f1) << 16);
            }
            *(unsigned*)&Bs[bcol * LDK + k] = pw;
        }
        __syncthreads();
        bf16x8 a0 = *(const bf16x8*)&As[(wm + lr) * LDK + kg * 8];
        bf16x8 a1 = *(const bf16x8*)&As[(wm + 16 + lr) * LDK + kg * 8];
        bf16x8 b0 = *(const bf16x8*)&Bs[(wn + lr) * LDK + kg * 8];
        bf16x8 b1 = *(const bf16x8*)&Bs[(wn + 16 + lr) * LDK + kg * 8];
        acc00 = __builtin_amdgcn_mfma_f32_16x16x32_bf16(a0, b0, acc00, 0, 0, 0);
        acc01 = __builtin_amdgcn_mfma_f32_16x16x32_bf16(a0, b1, acc01, 0, 0, 0);
        acc10 = __builtin_amdgcn_mfma_f32_16x16x32_bf16(a1, b0, acc10, 0, 0, 0);
        acc11 = __builtin_amdgcn_mfma_f32_16x16x32_bf16(a1, b1, acc11, 0, 0, 0);
        __syncthreads();
    }
#pragma unroll
    for (int i = 0; i < 2; ++i) {
        int rbase = bm + wm + i * 16 + kg * 4;
#pragma unroll
        for (int j = 0; j < 2; ++j) {
            int col = bn + wn + j * 16 + lr;
            if (col >= Ncols) continue;
            float bv = (col < split) ? (bias0 ? bias0[col] : 0.0f)
                                     : (bias1 ? bias1[col - split] : 0.0f);
            f32x4 a = (i == 0) ? (j == 0 ? acc00 : acc01) : (j == 0 ? acc10 : acc11);
#pragma unroll
            for (int r = 0; r < 4; ++r) {
                int row = rbase + r;
                if (row >= Nrows) continue;
                float o = a[r] + bv;
                if (relu) o = fmaxf(o, 0.0f);
                if (cbf_mode == 2)
                    Cbf[(size_t)row * ldcbf + col] = (ushort_t)f2bf(o);
                else if (cbf_mode == 1 && col >= split)
                    Cbf[(size_t)row * 128 + (col - split)] = (ushort_t)f2bf(o);
                else
                    C[(size_t)row * ldc + col] = o;
            }
        }
    }
}

// t = segsum(hWb); x1 = relu(G2a + t + b2) — fused epilogue, depth-1 row prefetch.
__global__ void segsum_combine1_kernel(const ushort_t* __restrict__ hb,
                                       const int* __restrict__ rowptr, const int* __restrict__ colidx,
                                       const float* __restrict__ wnorm,
                                       const float* __restrict__ G2a, const float* __restrict__ b2,
                                       float* __restrict__ x1, int n) {
    int node = (blockIdx.x * blockDim.x + threadIdx.x) >> 6;
    if (node >= n) return;
    int lane = threadIdx.x & 63;
    int grp = lane >> 4;
    int l = lane & 15;
    int j0 = rowptr[node], j1 = rowptr[node + 1];
    float acc[8] = {};
    int j = j0 + grp;
    if (j < j1) {
        float w = wnorm[j];
        int c = colidx[j];
        uint4 r = ((const uint4*)(hb + (size_t)c * 128))[l];
        for (;;) {
            int jn = j + 4;
            bool more = jn < j1;
            float wn = 0.0f;
            uint4 rn = r;
            if (more) {
                int cn = colidx[jn];
                wn = wnorm[jn];
                rn = ((const uint4*)(hb + (size_t)cn * 128))[l];
            }
            acc[0] += w * bflo(r.x); acc[1] += w * bfhi(r.x);
            acc[2] += w * bflo(r.y); acc[3] += w * bfhi(r.y);
            acc[4] += w * bflo(r.z); acc[5] += w * bfhi(r.z);
            acc[6] += w * bflo(r.w); acc[7] += w * bfhi(r.w);
            if (!more) break;
            j = jn; w = wn; r = rn;
        }
    }
#pragma unroll
    for (int k = 0; k < 8; ++k) {
        acc[k] += __shfl_xor(acc[k], 16, 64);
        acc[k] += __shfl_xor(acc[k], 32, 64);
    }
    if (grp == 0) {
        int f = l * 8;
        if (f < 100) {
            float4 g0 = *(const float4*)&G2a[(size_t)node * 100 + f];
            float4 bv0 = *(const float4*)&b2[f];
            float4 o0;
            o0.x = fmaxf(g0.x + acc[0] + bv0.x, 0.0f);
            o0.y = fmaxf(g0.y + acc[1] + bv0.y, 0.0f);
            o0.z = fmaxf(g0.z + acc[2] + bv0.z, 0.0f);
            o0.w = fmaxf(g0.w + acc[3] + bv0.w, 0.0f);
            *(float4*)&x1[(size_t)node * 100 + f] = o0;
            if (f + 8 <= 100) {
                float4 g1 = *(const float4*)&G2a[(size_t)node * 100 + f + 4];
                float4 bv1 = *(const float4*)&b2[f + 4];
                float4 o1;
                o1.x = fmaxf(g1.x + acc[4] + bv1.x, 0.0f);
                o1.y = fmaxf(g1.y + acc[5] + bv1.y, 0.0f);
                o1.z = fmaxf(g1.z + acc[6] + bv1.z, 0.0f);
                o1.w = fmaxf(g1.w + acc[7] + bv1.w, 0.0f);
                *(float4*)&x1[(size_t)node * 100 + f + 4] = o1;
            }
        }
    }
}

// xo = x1 + relu(S[:,0:100]); zf = fp8(x1 + relu(S[:,100:200]));
// sv[i] = xo[i,:] @ w3b (fused rowdot via 32-lane shfl reduce).
__global__ void combine2_kernel(const float* __restrict__ S, const float* __restrict__ x1,
                                const float* __restrict__ w3b,
                                float* __restrict__ xo, unsigned* __restrict__ zf,
                                float* __restrict__ sv, int n) {
    int idx = blockIdx.x * blockDim.x + threadIdx.x;
    if (idx >= n * 32) return;
    int i = idx >> 5, q = idx & 31;
    unsigned w = 0u;
    float part = 0.0f;
    if (q < 25) {
        float4 s1 = *(const float4*)&S[(size_t)i * 200 + q * 4];
        float4 s2 = *(const float4*)&S[(size_t)i * 200 + 100 + q * 4];
        float4 xv = *(const float4*)&x1[(size_t)i * 100 + q * 4];
        float4 a, b;
        a.x = xv.x + fmaxf(s1.x, 0.0f); a.y = xv.y + fmaxf(s1.y, 0.0f);
        a.z = xv.z + fmaxf(s1.z, 0.0f); a.w = xv.w + fmaxf(s1.w, 0.0f);
        b.x = xv.x + fmaxf(s2.x, 0.0f); b.y = xv.y + fmaxf(s2.y, 0.0f);
        b.z = xv.z + fmaxf(s2.z, 0.0f); b.w = xv.w + fmaxf(s2.w, 0.0f);
        *(float4*)&xo[(size_t)i * 100 + q * 4] = a;
        w = (unsigned)__builtin_amdgcn_cvt_pk_fp8_f32(b.x, b.y, 0, false);
        w = (unsigned)__builtin_amdgcn_cvt_pk_fp8_f32(b.z, b.w, (int)w, true);
        float4 wv = *(const float4*)&w3b[q * 4];
        part = a.x * wv.x + a.y * wv.y + a.z * wv.z + a.w * wv.w;
    }
    zf[(size_t)i * 32 + q] = w;
#pragma unroll
    for (int off = 16; off > 0; off >>= 1)
        part += __shfl_xor(part, off, 32);
    if (q == 0) sv[i] = part;
}

// fused pos/neg loss on fp8 z rows: 8 lanes/edge, uint4/lane = full 128B row.
// Direct ei/nei reads (no pair tables). Two independent edge streams per group,
// each with depth-2 index + depth-1 row prefetch.
__global__ __launch_bounds__(256) void edge_loss_fp8_kernel(
    const unsigned* __restrict__ zf, const int* __restrict__ ei,
    const int* __restrict__ nei, int E, float* __restrict__ accv) {
    const int y = blockIdx.y;
    const int* __restrict__ lst = y ? nei : ei;
    const int l = threadIdx.x & 7;
    const int g = (blockIdx.x * blockDim.x + threadIdx.x) >> 3;
    const int ng = (gridDim.x * blockDim.x) >> 3;
    const int stride2 = 2 * ng;
    float s = 0.0f;
    const int gA = g, gB = g + ng;
    int niterA = (gA < E) ? ((E - 1 - gA) / stride2 + 1) : 0;
    int niterB = (gB < E) ? ((E - 1 - gB) / stride2 + 1) : 0;
    if (niterA > 0) {
        int eB0 = (gB < E) ? gB : (E - 1);
        int eA1 = (gA + stride2 < E) ? (gA + stride2) : (E - 1);
        int eB1 = (gB + stride2 < E) ? (gB + stride2) : (E - 1);
        int aA0 = lst[gA], bA0 = lst[E + gA];
        int aB0 = lst[eB0], bB0 = lst[E + eB0];
        int aA1 = lst[eA1], bA1 = lst[E + eA1];
        int aB1 = lst[eB1], bB1 = lst[E + eB1];
        uint4 raA = *(const uint4*)&zf[(size_t)aA0 * 32 + l * 4];
        uint4 rbA = *(const uint4*)&zf[(size_t)bA0 * 32 + l * 4];
        uint4 raB = *(const uint4*)&zf[(size_t)aB0 * 32 + l * 4];
        uint4 rbB = *(const uint4*)&zf[(size_t)bB0 * 32 + l * 4];
        for (int t = 0; t < niterA; ++t) {
            int eA2 = gA + (t + 2) * stride2; eA2 = (eA2 < E) ? eA2 : (E - 1);
            int eB2 = gB + (t + 2) * stride2; eB2 = (eB2 < E) ? eB2 : (E - 1);
            int aA2 = lst[eA2], bA2 = lst[E + eA2];
            int aB2 = lst[eB2], bB2 = lst[E + eB2];
            uint4 raA1 = *(const uint4*)&zf[(size_t)aA1 * 32 + l * 4];
            uint4 rbA1 = *(const uint4*)&zf[(size_t)bA1 * 32 + l * 4];
            uint4 raB1 = *(const uint4*)&zf[(size_t)aB1 * 32 + l * 4];
            uint4 rbB1 = *(const uint4*)&zf[(size_t)bB1 * 32 + l * 4];
            float dA = dot16fp8(raA, rbA);
            float dB = dot16fp8(raB, rbB);
            dA += __shfl_xor(dA, 1, 8); dB += __shfl_xor(dB, 1, 8);
            dA += __shfl_xor(dA, 2, 8); dB += __shfl_xor(dB, 2, 8);
            dA += __shfl_xor(dA, 4, 8); dB += __shfl_xor(dB, 4, 8);
            if (l == 0) {
                float sgA = 1.0f / (1.0f + expf(-dA));
                s += y ? logf(1.0f - sgA + 1e-15f) : logf(sgA + 1e-15f);
                if (t < niterB) {
                    float sgB = 1.0f / (1.0f + expf(-dB));
                    s += y ? logf(1.0f - sgB + 1e-15f) : logf(sgB + 1e-15f);
                }
            }
            aA1 = aA2; bA1 = bA2; aB1 = aB2; bB1 = bB2;
            raA = raA1; rbA = rbA1; raB = raB1; rbB = rbB1;
        }
    }
    __shared__ float red[256];
    red[threadIdx.x] = s;
    __syncthreads();
    for (int st = 128; st > 0; st >>= 1) {
        if (threadIdx.x < st) red[threadIdx.x] += red[threadIdx.x + st];
        __syncthreads();
    }
    if (threadIdx.x == 0) atomicAdd(&accv[y], red[0]);
}

// out[i] = xo[i,:]@W3[0] + b3 + sum_j wnorm[j]*sv[colidx[j]]; thread 0 writes
// r_loss/c1/c2 tail (acc is final: edge_loss precedes on stream).
__global__ void out_finalize_kernel(const float* __restrict__ xo, const float* __restrict__ W3,
                                    const float* __restrict__ b3, const int* __restrict__ rowptr,
                                    const int* __restrict__ colidx, const float* __restrict__ wnorm,
                                    const float* __restrict__ sv, const float* __restrict__ accv,
                                    const float* __restrict__ c1, const float* __restrict__ c2,
                                    float* __restrict__ out, int n, int E) {
    int i = blockIdx.x * blockDim.x + threadIdx.x;
    if (i == 0) {
        out[n]     = -(accv[0] + accv[1]) / (float)E;
        out[n + 1] = c1[0];
        out[n + 2] = c2[0];
    }
    if (i >= n) return;
    const float4* a = (const float4*)(xo + (size_t)i * 100);
    const float4* wv = (const float4*)W3;
    float acc = b3[0];
#pragma unroll
    for (int q = 0; q < 25; ++q) {
        float4 va = a[q], vw = wv[q];
        acc += va.x * vw.x + va.y * vw.y + va.z * vw.z + va.w * vw.w;
    }
    int j1 = rowptr[i + 1];
    for (int j = rowptr[i]; j < j1; ++j)
        acc += wnorm[j] * sv[colidx[j]];
    out[i] = acc;
}

extern "C" void kernel_launch(void* const* d_in, const int* in_sizes, int n_in,
                              void* d_out, int out_size, void* d_ws, size_t ws_size,
                              hipStream_t stream) {
    (void)n_in; (void)out_size; (void)ws_size;
    const float* x   = (const float*)d_in[0];
    const int*   ei  = (const int*)d_in[1];
    const int*   nei = (const int*)d_in[2];
    const float* W1  = (const float*)d_in[3];
    const float* b1  = (const float*)d_in[4];
    const float* W2  = (const float*)d_in[5];
    const float* b2  = (const float*)d_in[6];
    const float* W3  = (const float*)d_in[7];
    const float* b3  = (const float*)d_in[8];
    const float* lw1 = (const float*)d_in[9];
    const float* lb1 = (const float*)d_in[10];
    const float* lw2 = (const float*)d_in[11];
    const float* lb2 = (const float*)d_in[12];
    const float* c1  = (const float*)d_in[13];
    const float* c2  = (const float*)d_in[14];

    const int Nn = in_sizes[0] / 64;   // 13627
    const int E  = in_sizes[1] / 2;    // 504378

    const size_t Nal = ((size_t)Nn + 5) & ~(size_t)3;   // >= N+1, mult of 4
    const size_t Eal = ((size_t)E + 3) & ~(size_t)3;
    const int LDH = 304;               // h bf16 row stride (300 padded, 16B-mult)

    float* ws       = (float*)d_ws;
    float* acc      = ws;                           // 4 floats
    float* dinv     = acc + 4;                      // Nal
    int*   rowptr   = (int*)(dinv + Nal);           // Nal (N+1 used)
    int*   colidx   = rowptr + Nal;                 // Eal
    float* wnorm    = (float*)(colidx + Eal);       // Eal
    int*   degp     = (int*)(wnorm + Eal);          // HB*PACKN ints
    int*   cntp     = degp + (size_t)HB * PACKN;    // HB*PACKN ints
    ushort_t* offus = (ushort_t*)(cntp + (size_t)HB * PACKN);  // HB*Nal ushorts
    ushort_t* xb    = offus + (size_t)HB * Nal;     // N*64 bf16 (128B rows)
    ushort_t* XTb   = xb + (size_t)Nn * 64;         // N*128 bf16
    ushort_t* hb    = XTb + (size_t)Nn * 128;       // N*304 bf16
    float* G2a      = (float*)(hb + (size_t)Nn * LDH);  // N*100 (float-aligned: offsets even)
    float* x1       = G2a + (size_t)Nn * 100;       // N*100
    float* xo       = x1 + (size_t)Nn * 100;        // N*100
    float* S        = xo + (size_t)Nn * 100;        // N*200
    size_t zoff     = (size_t)(S + (size_t)Nn * 200 - ws);
    zoff = (zoff + 31) & ~(size_t)31;               // 128B align
    unsigned* zf    = (unsigned*)(ws + zoff);       // N*32 words (fp8 rows, 128B)
    size_t hoff2    = zoff + (size_t)Nn * 32 + 63;
    hoff2 &= ~(size_t)63;                           // 256B align
    ushort_t* hWb   = (ushort_t*)(ws + hoff2);      // N*128 bf16 (256B rows)
    float* sv       = ws + hoff2 + (size_t)Nn * 64; // Nal
    const int MB = (Nn + GBM - 1) / GBM;

    // --- CSR build (packed LDS histograms, no global atomics) + x bf16 pack ---
    hist_both_x_kernel<<<HB, 512, 0, stream>>>(ei, x, degp, cntp, xb, Nn, E);
    merge_kernel<<<(4 * Nn + 255) / 256, 256, 0, stream>>>(degp, cntp, offus, (int)Nal,
                                                           dinv, rowptr, acc, Nn);
    scan_kernel<<<1, 1024, 0, stream>>>(rowptr, Nn);
    fill_lds_kernel<<<HB, 512, 0, stream>>>(ei, dinv, rowptr, offus, (int)Nal,
                                            colidx, wnorm, E);

    // --- conv1: XTb = [xb | bf16(segsum64(xb))]; hb = bf16(relu(XTb @ W1 + b1)) ---
    xt_kernel<<<(Nn + 3) / 4, 256, 0, stream>>>(xb, rowptr, colidx, wnorm, XTb, Nn);
    gemm_mfma<<<dim3(5, MB), 256, 0, stream>>>(
        nullptr, XTb, 128, W1, nullptr, b1, nullptr,
        nullptr, 0, hb, LDH, 2, Nn, 128, 300, 300, 1);

    // --- conv2 fused: [G2a | hWb(bf16)] = hb @ [W2[0] | W2[1]] ---
    gemm_mfma<<<dim3(4, MB), 256, 0, stream>>>(
        nullptr, hb, LDH, W2, W2 + 300 * 100, nullptr, nullptr,
        G2a, 100, hWb, 0, 1, Nn, 300, 200, 100, 0);
    // x1 = relu(G2a + segsum(hWb) + b2) fused
    segsum_combine1_kernel<<<(Nn + 3) / 4, 256, 0, stream>>>(hWb, rowptr, colidx, wnorm,
                                                             G2a, b2, x1, Nn);

    // --- skips fused: S = xb @ [lw1|lw2] + [lb1|lb2];
    //     combine2: xo = x1+relu(S0), zf = fp8(x1+relu(S1)), sv = xo@W3[1] ---
    gemm_mfma<<<dim3(4, MB), 256, 0, stream>>>(
        nullptr, xb, 64, lw1, lw2, lb1, lb2,
        S, 200, nullptr, 0, 0, Nn, 64, 200, 100, 0);
    combine2_kernel<<<(Nn * 32 + 255) / 256, 256, 0, stream>>>(S, x1, W3 + 100,
                                                               xo, zf, sv, Nn);

    // --- edge reconstruction losses (pos: y=0, neg: y=1), fp8 z, direct ei/nei ---
    edge_loss_fp8_kernel<<<dim3(1024, 2), 256, 0, stream>>>(zf, ei, nei, E, acc);

    // --- conv3 (width 1) + finalize: out = xo@W3[0] + segsum(sv) + b3; tail ---
    out_finalize_kernel<<<(Nn + 255) / 256, 256, 0, stream>>>(
        xo, W3, b3, rowptr, colidx, wnorm, sv, acc, c1, c2, (float*)d_out, Nn, E);
}